// Round 6
// baseline (564.159 us; speedup 1.0000x reference)
//
#include <hip/hip_runtime.h>

#define CH    256
#define NTOK  2304
#define MATSZ (CH * NTOK)   // 589824 elements per (b, matrix)

typedef __bf16 bf16x8 __attribute__((ext_vector_type(8)));
typedef float  f4v    __attribute__((ext_vector_type(4)));
typedef float  f16v   __attribute__((ext_vector_type(16)));
typedef unsigned int u32x4 __attribute__((ext_vector_type(4)));

__device__ __forceinline__ unsigned short f2bf(float f) {
    union { float f; unsigned int i; } c;
    c.f = f;
    unsigned int x = c.i;
    x += 0x7fffu + ((x >> 16) & 1u);   // round-to-nearest-even
    return (unsigned short)(x >> 16);
}

__device__ __forceinline__ bf16x8 cvt8(const float* p) {
    union { bf16x8 v; unsigned short s[8]; } u;
#pragma unroll
    for (int i = 0; i < 8; ++i) u.s[i] = f2bf(p[i]);
    return u.v;
}

// ---------------------------------------------------------------------------
// 64x64-tiled transpose + fp32->bf16 (unchanged — HW-verified)
// ---------------------------------------------------------------------------
__global__ __launch_bounds__(256) void tpose_k(
    const float* __restrict__ inL,
    const float* __restrict__ inR,
    unsigned short* __restrict__ out, int R, int Ccols)
{
    __shared__ unsigned short tile[64][72];
    int mat = blockIdx.y;
    const float* in = (mat >= 8 ? inR : inL) + (size_t)(mat & 7) * MATSZ;
    unsigned short* o = out + (size_t)mat * MATSZ;
    int tC = Ccols >> 6;
    int r0 = (blockIdx.x / tC) << 6;
    int c0 = (blockIdx.x % tC) << 6;
    int t = threadIdx.x;
    int col = t & 63, rs = t >> 6;
#pragma unroll
    for (int i = 0; i < 16; ++i) {
        int row = rs + i * 4;
        tile[row][col] = f2bf(in[(size_t)(r0 + row) * Ccols + c0 + col]);
    }
    __syncthreads();
#pragma unroll
    for (int i = 0; i < 16; ++i) {
        int crow = rs + i * 4;
        o[(size_t)(c0 + crow) * R + r0 + col] = tile[col][crow];
    }
}

// ---------------------------------------------------------------------------
// Projection (unchanged — HW-verified)
// ---------------------------------------------------------------------------
__global__ __launch_bounds__(256, 2) void proj_k(
    const unsigned short* __restrict__ XT,   // [2][8][2304][256] bf16
    const float* __restrict__ Wq_, const float* __restrict__ Wk_,
    const float* __restrict__ bq_, const float* __restrict__ bk_,
    const float* __restrict__ gq_, const float* __restrict__ gk_,
    const float* __restrict__ beq_, const float* __restrict__ bek_,
    const float* __restrict__ mq_, const float* __restrict__ mk_,
    const float* __restrict__ vq_, const float* __restrict__ vk_,
    unsigned short* __restrict__ Yout)       // [4][8][MATSZ] bf16
{
    __shared__ __align__(16) unsigned short Xs[64][264];
    int pb = blockIdx.y;
    int p = pb >> 3, b = pb & 7;
    int s = p & 1, br = p >> 1;
    const unsigned short* X = XT + (size_t)(s * 8 + b) * MATSZ;
    const float* W  = br ? Wk_ : Wq_;
    const float* bb = br ? bk_ : bq_;
    const float* gg = br ? gk_ : gq_;
    const float* be = br ? bek_ : beq_;
    const float* mm = br ? mk_ : mq_;
    const float* vv = br ? vk_ : vq_;
    unsigned short* Yo = Yout + (size_t)pb * MATSZ;

    int ot = blockIdx.x & 3, pt = blockIdx.x >> 2;
    int o0 = ot * 64, pos0 = pt * 64;
    int t = threadIdx.x;
    int w = t >> 6, lane = t & 63;
    int l15 = lane & 15, quad = lane >> 4;

    {   // stage XT tile: 64 pos-rows x 256 c
        int r = t >> 2, cq = (t & 3) << 6;
        const unsigned short* src = X + (size_t)(pos0 + r) * CH + cq;
        unsigned short* dst = &Xs[r][cq];
#pragma unroll
        for (int k = 0; k < 8; ++k)
            *(u32x4*)(dst + k * 8) = *(const u32x4*)(src + k * 8);
    }
    bf16x8 wf[8];
    {
        const float* wp = W + (size_t)(o0 + w * 16 + l15) * CH + quad * 8;
#pragma unroll
        for (int kc = 0; kc < 8; ++kc)
            wf[kc] = cvt8(wp + kc * 32);
    }
    __syncthreads();

    f4v zero4 = {0.f, 0.f, 0.f, 0.f};
    f4v acc[4] = {zero4, zero4, zero4, zero4};
#pragma unroll
    for (int kc = 0; kc < 8; ++kc) {
#pragma unroll
        for (int ct = 0; ct < 4; ++ct) {
            bf16x8 xb = *(const bf16x8*)(&Xs[ct * 16 + l15][kc * 32 + quad * 8]);
            acc[ct] = __builtin_amdgcn_mfma_f32_16x16x32_bf16(wf[kc], xb, acc[ct], 0, 0, 0);
        }
    }
#pragma unroll
    for (int r = 0; r < 4; ++r) {
        int o = o0 + w * 16 + quad * 4 + r;
        float scale = gg[o] * rsqrtf(vv[o] + 1e-5f);
        float shift = (bb[o] - mm[o]) * scale + be[o];
#pragma unroll
        for (int ct = 0; ct < 4; ++ct) {
            float val = acc[ct][r] * scale + shift;
            Yo[(size_t)o * NTOK + pos0 + ct * 16 + l15] = f2bf(val);
        }
    }
}

// ---------------------------------------------------------------------------
// Fused attention R6: R4 compute (32x32x16) with the staging drain removed.
//  * V: NO LDS staging — vf B-frags read DIRECT from global/L2 (byte-
//    identical to what R4's Vs held; VT rows linear, 16B aligned).
//  * K: double-buffered [2][64key][512B] in LDS via global_load_lds with
//    COUNTED vmcnt + raw s_barrier. Per tile: issue 16 vf loads, then 8
//    glld(kt+1) -> other buf, then s_waitcnt vmcnt(24): in-order retirement
//    drains exactly the 8 glld(kt); the 24 newer (16 vf + 8 glld(kt+1))
//    stay in flight across BOTH barriers. kt=35 wraps prefetch to tile 0
//    (redundant but keeps the count uniform; buf0's last reader was kt=34).
//    Compiler's own wait for the newest vf is vmcnt(8) -> never drains the
//    prefetch. Empty asm memory fences after each s_barrier stop LDS reads
//    hoisting above the sync (the barrier builtin is not a compiler fence).
//  * Pb hazard: PV(kt) reads precede B1(kt+1) which precedes P-writes(kt+1).
//  * K-buf hazard: glld(kt+1)->buf^1; last reader QK^T(kt-1) done at B2(kt-1).
//  * launch_bounds(256,1): R5 post-mortem — (256,2) capped VGPRs at 128 and
//    spilled/sank the prefetch. Demand here ~230 (qf64+acc64+vf64+lacc16);
//    <=256 keeps 8 waves/CU (LDS 74240B -> 2 blocks/CU either way).
// ---------------------------------------------------------------------------
__global__ __launch_bounds__(256, 1) void attn_k(
    const unsigned short* __restrict__ Y,    // [4][8][MATSZ] projections bf16
    const unsigned short* __restrict__ VT,   // [2][8][256][2304] bf16
    float* __restrict__ out)                 // [2][8][MATSZ] fp32
{
    __shared__ __align__(16) unsigned char lds[74240];
    unsigned char* Ks = lds;                    // 2 x 32768 (double buffer)
    unsigned char* Pb = lds + 65536;            // 8192
    float*         Ls = (float*)(lds + 73728);  // [4][32] f32

    int bid = blockIdx.x;
    int wg = (bid & 7) * 72 + (bid >> 3);   // XCD swizzle (576 = 8*72, bijective)
    int qt = wg % 36;
    int ab = wg / 36;
    int a = ab >> 3, b = ab & 7;
    const unsigned short* Qp = Y + (size_t)(a * 8 + b) * MATSZ;        // q(l)/q(r)
    const unsigned short* Kp = Y + (size_t)((3 - a) * 8 + b) * MATSZ;  // k(r)/k(l)
    const unsigned short* Vp = VT + (size_t)((1 - a) * 8 + b) * MATSZ;
    float* Op = out + (size_t)ab * MATSZ;

    int t = threadIdx.x;
    int w = t >> 6, lane = t & 63;
    int l31 = lane & 31, h = lane >> 5;
    int qb = w >> 1;             // q-block
    int kb = w & 1;              // key-block (QK^T)
    int chh = w & 1;             // channel-half (PV)
    int rxor = (l31 & 7) << 4;   // read-side swizzle

    // K staging: linear LDS dest, inverse-swizzled global source (R4 map)
    const unsigned char* kS = (const unsigned char*)Kp
        + ((t * 16) ^ (((t >> 5) & 7) << 4));   // + kt*32768 + k*4096
    unsigned char* kD = Ks + t * 16;            // + buf*32768 + k*4096
    // V direct-read base: lane (l31,h) -> row chh*128+chb*32+l31, 16B chunk
    const unsigned short* VpT = Vp + (size_t)(chh * 128 + l31) * NTOK + h * 8;

    // Q fragments in registers (R4-verified map)
    bf16x8 qf[16];
    {
        const unsigned short* qp = Qp + (size_t)(qt * 64 + qb * 32 + l31) * CH + h * 8;
#pragma unroll
        for (int ks = 0; ks < 16; ++ks)
            qf[ks] = *(const bf16x8*)(qp + ks * 16);
    }

    f16v acc_o[4];
#pragma unroll
    for (int c = 0; c < 4; ++c)
#pragma unroll
        for (int r = 0; r < 16; ++r) acc_o[c][r] = 0.f;
    float l_acc[16];
#pragma unroll
    for (int r = 0; r < 16; ++r) l_acc[r] = 0.f;

    // prologue: stage K tile 0 -> buf0
#pragma unroll
    for (int k = 0; k < 8; ++k)
        __builtin_amdgcn_global_load_lds(
            (const unsigned int*)(kS + k * 4096),
            (unsigned int*)(kD + k * 4096), 16, 0, 0);

    for (int kt = 0; kt < 36; ++kt) {
        // ---- V fragments for this tile, direct from L2 (issued FIRST)
        bf16x8 vf[4][4];
        {
            const unsigned short* vp = VpT + kt * 64;
#pragma unroll
            for (int chb = 0; chb < 4; ++chb)
#pragma unroll
                for (int ks2 = 0; ks2 < 4; ++ks2)
                    vf[chb][ks2] = *(const bf16x8*)(vp + (size_t)chb * 32 * NTOK + ks2 * 16);
        }
        // ---- issue K(kt+1) prefetch into the other buffer
        {
            int nt = kt + 1; if (nt == 36) nt = 0;   // wrap: uniform vmcnt count
            const unsigned char* ks_src = kS + (size_t)nt * 32768;
            unsigned char* ks_dst = kD + ((kt + 1) & 1) * 32768;
#pragma unroll
            for (int k = 0; k < 8; ++k)
                __builtin_amdgcn_global_load_lds(
                    (const unsigned int*)(ks_src + k * 4096),
                    (unsigned int*)(ks_dst + k * 4096), 16, 0, 0);
        }
        // drain ONLY glld(kt): 24 newer ops (16 vf + 8 glld(kt+1)) remain
        asm volatile("s_waitcnt vmcnt(24)" ::: "memory");
        __builtin_amdgcn_s_barrier();            // B1: K(kt) visible to all
        asm volatile("" ::: "memory");           // no LDS read hoists above B1

        // ---- QK^T: S[qb*32..+32][kb*32..+32], 16 k-steps
        f16v accs;
#pragma unroll
        for (int r = 0; r < 16; ++r) accs[r] = 0.f;
        const unsigned char* krow = Ks + (kt & 1) * 32768 + ((kb * 32 + l31) << 9);
#pragma unroll
        for (int ks = 0; ks < 16; ++ks) {
            bf16x8 kf = *(const bf16x8*)(krow + ((ks * 32 + h * 16) ^ rxor));
            accs = __builtin_amdgcn_mfma_f32_32x32x16_bf16(qf[ks], kf, accs, 0, 0, 0);
        }
        // ---- exp, partial row-sums, P write (C-layout row=(r&3)+8*(r>>2)+4h)
#pragma unroll
        for (int r = 0; r < 16; ++r) {
            float pe = __expf(accs[r] * (1.0f / 256.0f));
            l_acc[r] += pe;
            int row = (r & 3) + 8 * (r >> 2) + 4 * h;   // q within qb*32
            int q = qb * 32 + row;
            *(__bf16*)(Pb + q * 128 + ((kb * 64 + l31 * 2) ^ ((row & 7) << 4))) = (__bf16)pe;
        }
        asm volatile("s_waitcnt lgkmcnt(0)" ::: "memory");
        __builtin_amdgcn_s_barrier();            // B2: P(kt) visible
        asm volatile("" ::: "memory");

        // ---- PV: O[qb*32..+32][chh*128..+128]; V from registers
#pragma unroll
        for (int ks2 = 0; ks2 < 4; ++ks2) {
            bf16x8 pf = *(const bf16x8*)(Pb + ((qb * 32 + l31) << 7)
                                       + ((ks2 * 32 + h * 16) ^ rxor));
#pragma unroll
            for (int chb = 0; chb < 4; ++chb)
                acc_o[chb] = __builtin_amdgcn_mfma_f32_32x32x16_bf16(pf, vf[chb][ks2], acc_o[chb], 0, 0, 0);
        }
    }

    // ---- row-sum finalize: reduce over the 32 key-lanes (within each half)
#pragma unroll
    for (int r = 0; r < 16; ++r) {
        float rs = l_acc[r];
        rs += __shfl_xor(rs, 1, 64);
        rs += __shfl_xor(rs, 2, 64);
        rs += __shfl_xor(rs, 4, 64);
        rs += __shfl_xor(rs, 8, 64);
        rs += __shfl_xor(rs, 16, 64);
        l_acc[r] = rs;
    }
    if (l31 == 0) {   // lanes 0 and 32 publish their half's 16 rows
#pragma unroll
        for (int r = 0; r < 16; ++r) {
            int row = (r & 3) + 8 * (r >> 2) + 4 * h;
            Ls[w * 32 + row] = l_acc[r];
        }
    }
    __syncthreads();   // Ls visible (also drains the wrapped prefetch)
    float l_tot[16];
#pragma unroll
    for (int r = 0; r < 16; ++r) {
        int row = (r & 3) + 8 * (r >> 2) + 4 * h;
        l_tot[r] = Ls[w * 32 + row] + Ls[(w ^ 1) * 32 + row];  // kb0 + kb1
    }

    // ---- epilogue: normalize, swizzled fp32 transpose, coalesced stores
    float* Ot = (float*)lds;   // [256 ch][64 q] f32, dword-XOR ((c&7)<<2)
#pragma unroll
    for (int chb = 0; chb < 4; ++chb) {
        int c = chh * 128 + chb * 32 + l31;
        int cx = (c & 7) << 2;
#pragma unroll
        for (int rr = 0; rr < 4; ++rr) {
            f4v v4;
#pragma unroll
            for (int i = 0; i < 4; ++i)
                v4[i] = acc_o[chb][rr * 4 + i] / l_tot[rr * 4 + i];
            int q0 = qb * 32 + rr * 8 + h * 4;   // rows rr*8+{0..3}+4h consecutive
            *(f4v*)(Ot + c * 64 + (q0 ^ cx)) = v4;
        }
    }
    __syncthreads();
#pragma unroll
    for (int p = 0; p < 16; ++p) {
        int c = p * 16 + (t >> 4);
        int q = (t & 15) * 4;
        f4v v4 = *(const f4v*)(Ot + c * 64 + (q ^ ((c & 7) << 2)));
        *(f4v*)(Op + (size_t)c * NTOK + qt * 64 + q) = v4;
    }
}

// ---------------------------------------------------------------------------
extern "C" void kernel_launch(void* const* d_in, const int* in_sizes, int n_in,
                              void* d_out, int out_size, void* d_ws, size_t ws_size,
                              hipStream_t stream) {
    (void)in_sizes; (void)n_in; (void)out_size; (void)ws_size;
    const float* feaL  = (const float*)d_in[0];
    const float* feaR  = (const float*)d_in[1];
    const float* Wq    = (const float*)d_in[2];
    const float* bq    = (const float*)d_in[3];
    const float* gq    = (const float*)d_in[4];
    const float* betaq = (const float*)d_in[5];
    const float* mq    = (const float*)d_in[6];
    const float* vq    = (const float*)d_in[7];
    const float* Wk    = (const float*)d_in[8];
    const float* bk    = (const float*)d_in[9];
    const float* gk    = (const float*)d_in[10];
    const float* betak = (const float*)d_in[11];
    const float* mk    = (const float*)d_in[12];
    const float* vk    = (const float*)d_in[13];

    // workspace (bf16): XT/VT alias 16*MATSZ (18.9MB) | Y 32*MATSZ (37.7MB)
    unsigned short* XT = (unsigned short*)d_ws;   // reused as VT after proj
    unsigned short* VT = XT;
    unsigned short* Yb = XT + (size_t)16 * MATSZ;
    float* out = (float*)d_out;   // fp32: reference output dtype

    dim3 blk(256);
    // XT[s][b][pos][c] = fea[b][c][pos]
    tpose_k<<<dim3(144, 16), blk, 0, stream>>>(feaL, feaR, XT, 256, 2304);
    proj_k<<<dim3(144, 32), blk, 0, stream>>>(XT, Wq, Wk, bq, bk, gq, gk,
                                              betaq, betak, mq, mk, vq, vk, Yb);
    // VT[s][b][c][n] = fea_flat[n*256+c]
    tpose_k<<<dim3(144, 16), blk, 0, stream>>>(feaL, feaR, VT, 2304, 256);
    attn_k<<<dim3(576), blk, 0, stream>>>(Yb, VT, out);
}

// Round 8
// 428.074 us; speedup vs baseline: 1.3179x; 1.3179x over previous
//
#include <hip/hip_runtime.h>

#define CH    256
#define NTOK  2304
#define MATSZ (CH * NTOK)   // 589824 elements per (b, matrix)

typedef __bf16 bf16x8 __attribute__((ext_vector_type(8)));
typedef float  f4v    __attribute__((ext_vector_type(4)));
typedef float  f16v   __attribute__((ext_vector_type(16)));
typedef unsigned int u32x4 __attribute__((ext_vector_type(4)));

__device__ __forceinline__ unsigned short f2bf(float f) {
    union { float f; unsigned int i; } c;
    c.f = f;
    unsigned int x = c.i;
    x += 0x7fffu + ((x >> 16) & 1u);   // round-to-nearest-even
    return (unsigned short)(x >> 16);
}

__device__ __forceinline__ bf16x8 cvt8(const float* p) {
    union { bf16x8 v; unsigned short s[8]; } u;
#pragma unroll
    for (int i = 0; i < 8; ++i) u.s[i] = f2bf(p[i]);
    return u.v;
}

// ---------------------------------------------------------------------------
// 64x64-tiled transpose + fp32->bf16 (unchanged — HW-verified)
// ---------------------------------------------------------------------------
__global__ __launch_bounds__(256) void tpose_k(
    const float* __restrict__ inL,
    const float* __restrict__ inR,
    unsigned short* __restrict__ out, int R, int Ccols)
{
    __shared__ unsigned short tile[64][72];
    int mat = blockIdx.y;
    const float* in = (mat >= 8 ? inR : inL) + (size_t)(mat & 7) * MATSZ;
    unsigned short* o = out + (size_t)mat * MATSZ;
    int tC = Ccols >> 6;
    int r0 = (blockIdx.x / tC) << 6;
    int c0 = (blockIdx.x % tC) << 6;
    int t = threadIdx.x;
    int col = t & 63, rs = t >> 6;
#pragma unroll
    for (int i = 0; i < 16; ++i) {
        int row = rs + i * 4;
        tile[row][col] = f2bf(in[(size_t)(r0 + row) * Ccols + c0 + col]);
    }
    __syncthreads();
#pragma unroll
    for (int i = 0; i < 16; ++i) {
        int crow = rs + i * 4;
        o[(size_t)(c0 + crow) * R + r0 + col] = tile[col][crow];
    }
}

// ---------------------------------------------------------------------------
// Projection (unchanged — HW-verified)
// ---------------------------------------------------------------------------
__global__ __launch_bounds__(256, 2) void proj_k(
    const unsigned short* __restrict__ XT,   // [2][8][2304][256] bf16
    const float* __restrict__ Wq_, const float* __restrict__ Wk_,
    const float* __restrict__ bq_, const float* __restrict__ bk_,
    const float* __restrict__ gq_, const float* __restrict__ gk_,
    const float* __restrict__ beq_, const float* __restrict__ bek_,
    const float* __restrict__ mq_, const float* __restrict__ mk_,
    const float* __restrict__ vq_, const float* __restrict__ vk_,
    unsigned short* __restrict__ Yout)       // [4][8][MATSZ] bf16
{
    __shared__ __align__(16) unsigned short Xs[64][264];
    int pb = blockIdx.y;
    int p = pb >> 3, b = pb & 7;
    int s = p & 1, br = p >> 1;
    const unsigned short* X = XT + (size_t)(s * 8 + b) * MATSZ;
    const float* W  = br ? Wk_ : Wq_;
    const float* bb = br ? bk_ : bq_;
    const float* gg = br ? gk_ : gq_;
    const float* be = br ? bek_ : beq_;
    const float* mm = br ? mk_ : mq_;
    const float* vv = br ? vk_ : vq_;
    unsigned short* Yo = Yout + (size_t)pb * MATSZ;

    int ot = blockIdx.x & 3, pt = blockIdx.x >> 2;
    int o0 = ot * 64, pos0 = pt * 64;
    int t = threadIdx.x;
    int w = t >> 6, lane = t & 63;
    int l15 = lane & 15, quad = lane >> 4;

    {   // stage XT tile: 64 pos-rows x 256 c
        int r = t >> 2, cq = (t & 3) << 6;
        const unsigned short* src = X + (size_t)(pos0 + r) * CH + cq;
        unsigned short* dst = &Xs[r][cq];
#pragma unroll
        for (int k = 0; k < 8; ++k)
            *(u32x4*)(dst + k * 8) = *(const u32x4*)(src + k * 8);
    }
    bf16x8 wf[8];
    {
        const float* wp = W + (size_t)(o0 + w * 16 + l15) * CH + quad * 8;
#pragma unroll
        for (int kc = 0; kc < 8; ++kc)
            wf[kc] = cvt8(wp + kc * 32);
    }
    __syncthreads();

    f4v zero4 = {0.f, 0.f, 0.f, 0.f};
    f4v acc[4] = {zero4, zero4, zero4, zero4};
#pragma unroll
    for (int kc = 0; kc < 8; ++kc) {
#pragma unroll
        for (int ct = 0; ct < 4; ++ct) {
            bf16x8 xb = *(const bf16x8*)(&Xs[ct * 16 + l15][kc * 32 + quad * 8]);
            acc[ct] = __builtin_amdgcn_mfma_f32_16x16x32_bf16(wf[kc], xb, acc[ct], 0, 0, 0);
        }
    }
#pragma unroll
    for (int r = 0; r < 4; ++r) {
        int o = o0 + w * 16 + quad * 4 + r;
        float scale = gg[o] * rsqrtf(vv[o] + 1e-5f);
        float shift = (bb[o] - mm[o]) * scale + be[o];
#pragma unroll
        for (int ct = 0; ct < 4; ++ct) {
            float val = acc[ct][r] * scale + shift;
            Yo[(size_t)o * NTOK + pos0 + ct * 16 + l15] = f2bf(val);
        }
    }
}

// ---------------------------------------------------------------------------
// Fused attention R7 = R5 (R4 32x32x16 compute + R2 register-prefetch
// staging) with __launch_bounds__(256, 1).
//
// R5 post-mortem: (256,2) capped the allocator at 128 VGPRs; demand ~230 ->
// scratch spill (WRITE_SIZE +17.8MB) AND the compiler sank the prefetch
// loads to their use point, serializing the pipeline. R6 proved (256,1)
// lets VGPRs float with zero spill. R6 post-mortem: V must stay SHARED in
// LDS (per-wave private V loads = 4x L2 traffic in 32B-granular scatter).
//
// LDS layouts (HW-verified R2/R4/R5):
//   Ks [64 key][512B]  phys = key*512 + (off ^ ((key&7)<<4))
//   Vs [256 ch][128B]  phys = ch*128  + (off ^ ((ch&7)<<4))
//   Pb [64 q ][128B]   phys = q*128   + (off ^ ((q&7)<<4))
// Staging write map (R2-verified): flat f = k*4096 + t*16;
//   K: key = k*8+(t>>5)  -> kdst = Ks + (t*16 ^ ((t>>5&7)<<4)) + k*4096
//   V: ch  = k*32+(t>>3) -> vdst = Vs + (t*16 ^ ((t>>3&7)<<4)) + k*4096
// Pipeline: B0; ds_write(kt); B1; issue global loads(kt+1) -> regs;
// QK^T (hides load latency); P-write; B2 (implicit vmcnt drain lands after
// ~600cy of compute); PV. Compute/Pb/epilogue unchanged from R4/R5.
// ---------------------------------------------------------------------------
__global__ __launch_bounds__(256, 1) void attn_k(
    const unsigned short* __restrict__ Y,    // [4][8][MATSZ] projections bf16
    const unsigned short* __restrict__ VT,   // [2][8][256][2304] bf16
    float* __restrict__ out)                 // [2][8][MATSZ] fp32
{
    __shared__ __align__(16) unsigned char lds[74240];
    unsigned char* Ks = lds;                    // 32768
    unsigned char* Vs = lds + 32768;            // 32768
    unsigned char* Pb = lds + 65536;            // 8192
    float*         Ls = (float*)(lds + 73728);  // [4][32] f32

    int bid = blockIdx.x;
    int wg = (bid & 7) * 72 + (bid >> 3);   // XCD swizzle (576 = 8*72, bijective)
    int qt = wg % 36;
    int ab = wg / 36;
    int a = ab >> 3, b = ab & 7;
    const unsigned short* Qp = Y + (size_t)(a * 8 + b) * MATSZ;        // q(l)/q(r)
    const unsigned short* Kp = Y + (size_t)((3 - a) * 8 + b) * MATSZ;  // k(r)/k(l)
    const unsigned short* Vp = VT + (size_t)((1 - a) * 8 + b) * MATSZ;
    float* Op = out + (size_t)ab * MATSZ;

    int t = threadIdx.x;
    int w = t >> 6, lane = t & 63;
    int l31 = lane & 31, h = lane >> 5;
    int qb = w >> 1;             // q-block (QK^T and PV)
    int kb = w & 1;              // key-block (QK^T)
    int chh = w & 1;             // channel-half (PV)
    int rxor = (l31 & 7) << 4;   // read-side swizzle (row&7 == l31&7 everywhere)

    // staging: R2-verified register-prefetch maps
    const unsigned short* ksrc0 = Kp + t * 8;                          // + kt*16384 + k*2048 (shorts)
    const unsigned short* vsrc0 = Vp + (size_t)(t >> 3) * NTOK + ((t & 7) << 3);  // + kt*64 + k*32*NTOK
    char* kdst = (char*)Ks + ((t * 16) ^ (((t >> 5) & 7) << 4));       // + k*4096
    char* vdst = (char*)Vs + ((t * 16) ^ (((t >> 3) & 7) << 4));       // + k*4096

    // Q fragments in registers: rows qt*64 + qb*32 + l31, A-frag k = h*8+j
    bf16x8 qf[16];
    {
        const unsigned short* qp = Qp + (size_t)(qt * 64 + qb * 32 + l31) * CH + h * 8;
#pragma unroll
        for (int ks = 0; ks < 16; ++ks)
            qf[ks] = *(const bf16x8*)(qp + ks * 16);
    }

    f16v acc_o[4];
#pragma unroll
    for (int c = 0; c < 4; ++c)
#pragma unroll
        for (int r = 0; r < 16; ++r) acc_o[c][r] = 0.f;
    float l_acc[16];
#pragma unroll
    for (int r = 0; r < 16; ++r) l_acc[r] = 0.f;

    // preload tile kt=0 into registers
    u32x4 kreg[8], vreg[8];
#pragma unroll
    for (int k = 0; k < 8; ++k) kreg[k] = *(const u32x4*)(ksrc0 + k * 2048);
#pragma unroll
    for (int k = 0; k < 8; ++k) vreg[k] = *(const u32x4*)(vsrc0 + (size_t)k * 32 * NTOK);

    for (int kt = 0; kt < 36; ++kt) {
        __syncthreads();   // readers of tile kt-1 done (Ks, Vs, Pb)
#pragma unroll
        for (int k = 0; k < 8; ++k) *(u32x4*)(kdst + k * 4096) = kreg[k];
#pragma unroll
        for (int k = 0; k < 8; ++k) *(u32x4*)(vdst + k * 4096) = vreg[k];
        __syncthreads();   // staged tile visible

        if (kt < 35) {     // prefetch kt+1; lands during QK^T (~600cy)
            const unsigned short* kn = ksrc0 + (size_t)(kt + 1) * 16384;
            const unsigned short* vn = vsrc0 + (size_t)(kt + 1) * 64;
#pragma unroll
            for (int k = 0; k < 8; ++k) kreg[k] = *(const u32x4*)(kn + k * 2048);
#pragma unroll
            for (int k = 0; k < 8; ++k) vreg[k] = *(const u32x4*)(vn + (size_t)k * 32 * NTOK);
        }

        // ---- QK^T: S[qb*32..+32][kb*32..+32], 16 k-steps
        f16v accs;
#pragma unroll
        for (int r = 0; r < 16; ++r) accs[r] = 0.f;
        const unsigned char* krow = Ks + ((kb * 32 + l31) << 9);
#pragma unroll
        for (int ks = 0; ks < 16; ++ks) {
            bf16x8 kf = *(const bf16x8*)(krow + ((ks * 32 + h * 16) ^ rxor));
            accs = __builtin_amdgcn_mfma_f32_32x32x16_bf16(qf[ks], kf, accs, 0, 0, 0);
        }
        // ---- exp, partial row-sums, P write (C-layout row=(r&3)+8*(r>>2)+4h)
#pragma unroll
        for (int r = 0; r < 16; ++r) {
            float pe = __expf(accs[r] * (1.0f / 256.0f));
            l_acc[r] += pe;
            int row = (r & 3) + 8 * (r >> 2) + 4 * h;   // q within qb*32
            int q = qb * 32 + row;
            *(__bf16*)(Pb + q * 128 + ((kb * 64 + l31 * 2) ^ ((row & 7) << 4))) = (__bf16)pe;
        }
        __syncthreads();   // P(kt) visible to all waves

        // ---- PV: O[qb*32..+32][chh*128..+128]
#pragma unroll
        for (int ks2 = 0; ks2 < 4; ++ks2) {
            bf16x8 pf = *(const bf16x8*)(Pb + ((qb * 32 + l31) << 7)
                                       + ((ks2 * 32 + h * 16) ^ rxor));
#pragma unroll
            for (int chb = 0; chb < 4; ++chb) {
                int ch = chh * 128 + chb * 32 + l31;
                bf16x8 vf = *(const bf16x8*)(Vs + (ch << 7)
                                           + ((ks2 * 32 + h * 16) ^ rxor));
                acc_o[chb] = __builtin_amdgcn_mfma_f32_32x32x16_bf16(pf, vf, acc_o[chb], 0, 0, 0);
            }
        }
    }

    // ---- row-sum finalize: reduce over the 32 key-lanes (within each half)
#pragma unroll
    for (int r = 0; r < 16; ++r) {
        float rs = l_acc[r];
        rs += __shfl_xor(rs, 1, 64);
        rs += __shfl_xor(rs, 2, 64);
        rs += __shfl_xor(rs, 4, 64);
        rs += __shfl_xor(rs, 8, 64);
        rs += __shfl_xor(rs, 16, 64);
        l_acc[r] = rs;
    }
    if (l31 == 0) {   // lanes 0 and 32 publish their half's 16 rows
#pragma unroll
        for (int r = 0; r < 16; ++r) {
            int row = (r & 3) + 8 * (r >> 2) + 4 * h;
            Ls[w * 32 + row] = l_acc[r];
        }
    }
    __syncthreads();   // Ls visible; also fences last PV reads before Ot reuse
    float l_tot[16];
#pragma unroll
    for (int r = 0; r < 16; ++r) {
        int row = (r & 3) + 8 * (r >> 2) + 4 * h;
        l_tot[r] = Ls[w * 32 + row] + Ls[(w ^ 1) * 32 + row];  // kb0 + kb1
    }

    // ---- epilogue: normalize, swizzled fp32 transpose, coalesced stores
    float* Ot = (float*)lds;   // [256 ch][64 q] f32, dword-XOR ((c&7)<<2)
#pragma unroll
    for (int chb = 0; chb < 4; ++chb) {
        int c = chh * 128 + chb * 32 + l31;
        int cx = (c & 7) << 2;
#pragma unroll
        for (int rr = 0; rr < 4; ++rr) {
            f4v v4;
#pragma unroll
            for (int i = 0; i < 4; ++i)
                v4[i] = acc_o[chb][rr * 4 + i] / l_tot[rr * 4 + i];
            int q0 = qb * 32 + rr * 8 + h * 4;   // rows rr*8+{0..3}+4h consecutive
            *(f4v*)(Ot + c * 64 + (q0 ^ cx)) = v4;
        }
    }
    __syncthreads();
#pragma unroll
    for (int p = 0; p < 16; ++p) {
        int c = p * 16 + (t >> 4);
        int q = (t & 15) * 4;
        f4v v4 = *(const f4v*)(Ot + c * 64 + (q ^ ((c & 7) << 2)));
        *(f4v*)(Op + (size_t)c * NTOK + qt * 64 + q) = v4;
    }
}

// ---------------------------------------------------------------------------
extern "C" void kernel_launch(void* const* d_in, const int* in_sizes, int n_in,
                              void* d_out, int out_size, void* d_ws, size_t ws_size,
                              hipStream_t stream) {
    (void)in_sizes; (void)n_in; (void)out_size; (void)ws_size;
    const float* feaL  = (const float*)d_in[0];
    const float* feaR  = (const float*)d_in[1];
    const float* Wq    = (const float*)d_in[2];
    const float* bq    = (const float*)d_in[3];
    const float* gq    = (const float*)d_in[4];
    const float* betaq = (const float*)d_in[5];
    const float* mq    = (const float*)d_in[6];
    const float* vq    = (const float*)d_in[7];
    const float* Wk    = (const float*)d_in[8];
    const float* bk    = (const float*)d_in[9];
    const float* gk    = (const float*)d_in[10];
    const float* betak = (const float*)d_in[11];
    const float* mk    = (const float*)d_in[12];
    const float* vk    = (const float*)d_in[13];

    // workspace (bf16): XT/VT alias 16*MATSZ (18.9MB) | Y 32*MATSZ (37.7MB)
    unsigned short* XT = (unsigned short*)d_ws;   // reused as VT after proj
    unsigned short* VT = XT;
    unsigned short* Yb = XT + (size_t)16 * MATSZ;
    float* out = (float*)d_out;   // fp32: reference output dtype

    dim3 blk(256);
    // XT[s][b][pos][c] = fea[b][c][pos]
    tpose_k<<<dim3(144, 16), blk, 0, stream>>>(feaL, feaR, XT, 256, 2304);
    proj_k<<<dim3(144, 32), blk, 0, stream>>>(XT, Wq, Wk, bq, bk, gq, gk,
                                              betaq, betak, mq, mk, vq, vk, Yb);
    // VT[s][b][c][n] = fea_flat[n*256+c]
    tpose_k<<<dim3(144, 16), blk, 0, stream>>>(feaL, feaR, VT, 2304, 256);
    attn_k<<<dim3(576), blk, 0, stream>>>(Yb, VT, out);
}

// Round 10
// 321.328 us; speedup vs baseline: 1.7557x; 1.3322x over previous
//
#include <hip/hip_runtime.h>

#define CH    256
#define NTOK  2304
#define MATSZ (CH * NTOK)   // 589824 elements per (b, matrix)

typedef __bf16 bf16x8 __attribute__((ext_vector_type(8)));
typedef float  f4v    __attribute__((ext_vector_type(4)));
typedef float  f16v   __attribute__((ext_vector_type(16)));
typedef unsigned int u32x4 __attribute__((ext_vector_type(4)));

__device__ __forceinline__ unsigned short f2bf(float f) {
    union { float f; unsigned int i; } c;
    c.f = f;
    unsigned int x = c.i;
    x += 0x7fffu + ((x >> 16) & 1u);   // round-to-nearest-even
    return (unsigned short)(x >> 16);
}

__device__ __forceinline__ bf16x8 cvt8(const float* p) {
    union { bf16x8 v; unsigned short s[8]; } u;
#pragma unroll
    for (int i = 0; i < 8; ++i) u.s[i] = f2bf(p[i]);
    return u.v;
}

// ---------------------------------------------------------------------------
// 64x64-tiled transpose + fp32->bf16 (unchanged — HW-verified)
// ---------------------------------------------------------------------------
__global__ __launch_bounds__(256) void tpose_k(
    const float* __restrict__ inL,
    const float* __restrict__ inR,
    unsigned short* __restrict__ out, int R, int Ccols)
{
    __shared__ unsigned short tile[64][72];
    int mat = blockIdx.y;
    const float* in = (mat >= 8 ? inR : inL) + (size_t)(mat & 7) * MATSZ;
    unsigned short* o = out + (size_t)mat * MATSZ;
    int tC = Ccols >> 6;
    int r0 = (blockIdx.x / tC) << 6;
    int c0 = (blockIdx.x % tC) << 6;
    int t = threadIdx.x;
    int col = t & 63, rs = t >> 6;
#pragma unroll
    for (int i = 0; i < 16; ++i) {
        int row = rs + i * 4;
        tile[row][col] = f2bf(in[(size_t)(r0 + row) * Ccols + c0 + col]);
    }
    __syncthreads();
#pragma unroll
    for (int i = 0; i < 16; ++i) {
        int crow = rs + i * 4;
        o[(size_t)(c0 + crow) * R + r0 + col] = tile[col][crow];
    }
}

// ---------------------------------------------------------------------------
// Projection (unchanged — HW-verified)
// ---------------------------------------------------------------------------
__global__ __launch_bounds__(256, 2) void proj_k(
    const unsigned short* __restrict__ XT,   // [2][8][2304][256] bf16
    const float* __restrict__ Wq_, const float* __restrict__ Wk_,
    const float* __restrict__ bq_, const float* __restrict__ bk_,
    const float* __restrict__ gq_, const float* __restrict__ gk_,
    const float* __restrict__ beq_, const float* __restrict__ bek_,
    const float* __restrict__ mq_, const float* __restrict__ mk_,
    const float* __restrict__ vq_, const float* __restrict__ vk_,
    unsigned short* __restrict__ Yout)       // [4][8][MATSZ] bf16
{
    __shared__ __align__(16) unsigned short Xs[64][264];
    int pb = blockIdx.y;
    int p = pb >> 3, b = pb & 7;
    int s = p & 1, br = p >> 1;
    const unsigned short* X = XT + (size_t)(s * 8 + b) * MATSZ;
    const float* W  = br ? Wk_ : Wq_;
    const float* bb = br ? bk_ : bq_;
    const float* gg = br ? gk_ : gq_;
    const float* be = br ? bek_ : beq_;
    const float* mm = br ? mk_ : mq_;
    const float* vv = br ? vk_ : vq_;
    unsigned short* Yo = Yout + (size_t)pb * MATSZ;

    int ot = blockIdx.x & 3, pt = blockIdx.x >> 2;
    int o0 = ot * 64, pos0 = pt * 64;
    int t = threadIdx.x;
    int w = t >> 6, lane = t & 63;
    int l15 = lane & 15, quad = lane >> 4;

    {   // stage XT tile: 64 pos-rows x 256 c
        int r = t >> 2, cq = (t & 3) << 6;
        const unsigned short* src = X + (size_t)(pos0 + r) * CH + cq;
        unsigned short* dst = &Xs[r][cq];
#pragma unroll
        for (int k = 0; k < 8; ++k)
            *(u32x4*)(dst + k * 8) = *(const u32x4*)(src + k * 8);
    }
    bf16x8 wf[8];
    {
        const float* wp = W + (size_t)(o0 + w * 16 + l15) * CH + quad * 8;
#pragma unroll
        for (int kc = 0; kc < 8; ++kc)
            wf[kc] = cvt8(wp + kc * 32);
    }
    __syncthreads();

    f4v zero4 = {0.f, 0.f, 0.f, 0.f};
    f4v acc[4] = {zero4, zero4, zero4, zero4};
#pragma unroll
    for (int kc = 0; kc < 8; ++kc) {
#pragma unroll
        for (int ct = 0; ct < 4; ++ct) {
            bf16x8 xb = *(const bf16x8*)(&Xs[ct * 16 + l15][kc * 32 + quad * 8]);
            acc[ct] = __builtin_amdgcn_mfma_f32_16x16x32_bf16(wf[kc], xb, acc[ct], 0, 0, 0);
        }
    }
#pragma unroll
    for (int r = 0; r < 4; ++r) {
        int o = o0 + w * 16 + quad * 4 + r;
        float scale = gg[o] * rsqrtf(vv[o] + 1e-5f);
        float shift = (bb[o] - mm[o]) * scale + be[o];
#pragma unroll
        for (int ct = 0; ct < 4; ++ct) {
            float val = acc[ct][r] * scale + shift;
            Yo[(size_t)o * NTOK + pos0 + ct * 16 + l15] = f2bf(val);
        }
    }
}

// ---------------------------------------------------------------------------
// Fused attention R9 = R4 (32x32x16, glld staging, single-buffered K/V,
// LDS 74240B, (256,2)) with PHASE-SHIFTED glld issue + COUNTED vmcnt (T3/T4).
//
// R4 flaw (measured): glld(kt) issued then immediately drained at the stage
// barrier -> full L2 latency serial every tile. R8 proved reg-prefetch is
// dead (hipcc sinks the loads; VGPR=160 == no kreg/vreg allocated). glld
// has NO dest regs -> cannot be sunk; counted vmcnt keeps it in flight.
//
// Schedule (per tile kt; 3 barriers, same as R4):
//   1. s_waitcnt vmcnt(8)    -> drains K(kt) [issued ~1 iter ago]; V(kt) flies
//   2. B1                     K(kt) visible to all waves
//   3. QK^T(kt), exp, P-write
//   4. s_waitcnt vmcnt(0) lgkmcnt(0)  -> drains V(kt) [issued ~600cy ago]
//   5. B2                     P(kt)+V(kt) visible; K readers done
//   6. issue 8 glld K(kt+1)   (overwrite safe: K readers done at B2)
//   7. PV(kt)
//   8. B0                     V/P readers done
//   9. issue 8 glld V(kt+1)   (overwrite safe)
// In-flight sets are barrier-region-separated -> counts exact:
//   at (1): K(kt) 8 + V(kt) 8 = 16, drain oldest 8 = K ✓
//   at (4): V(kt) 8 only ✓
// Prologue: issue K(0) then V(0) (asm sep pins program order).
// kt=35 issues nothing (guarded); epilogue __syncthreads drains the rest.
//
// LDS layouts + staging maps HW-verified (R2/R4):
//   Ks [64 key][512B] phys=key*512+(off^((key&7)<<4)); src pre-swizzled
//   Vs [256 ch][128B] phys=ch*128 +(off^((ch&7)<<4));  linear glld dest
//   Pb [64 q ][128B]  phys=q*128  +(off^((q&7)<<4))
// Compute/Pb/epilogue byte-identical to R4.
// ---------------------------------------------------------------------------
__global__ __launch_bounds__(256, 2) void attn_k(
    const unsigned short* __restrict__ Y,    // [4][8][MATSZ] projections bf16
    const unsigned short* __restrict__ VT,   // [2][8][256][2304] bf16
    float* __restrict__ out)                 // [2][8][MATSZ] fp32
{
    __shared__ __align__(16) unsigned char lds[74240];
    unsigned char* Ks = lds;                    // 32768
    unsigned char* Vs = lds + 32768;            // 32768
    unsigned char* Pb = lds + 65536;            // 8192
    float*         Ls = (float*)(lds + 73728);  // [4][32] f32

    int bid = blockIdx.x;
    int wg = (bid & 7) * 72 + (bid >> 3);   // XCD swizzle (576 = 8*72, bijective)
    int qt = wg % 36;
    int ab = wg / 36;
    int a = ab >> 3, b = ab & 7;
    const unsigned short* Qp = Y + (size_t)(a * 8 + b) * MATSZ;        // q(l)/q(r)
    const unsigned short* Kp = Y + (size_t)((3 - a) * 8 + b) * MATSZ;  // k(r)/k(l)
    const unsigned short* Vp = VT + (size_t)((1 - a) * 8 + b) * MATSZ;
    float* Op = out + (size_t)ab * MATSZ;

    int t = threadIdx.x;
    int w = t >> 6, lane = t & 63;
    int l31 = lane & 31, h = lane >> 5;
    int qb = w >> 1;             // q-block (QK^T and PV)
    int kb = w & 1;              // key-block (QK^T)
    int chh = w & 1;             // channel-half (PV)
    int rxor = (l31 & 7) << 4;   // read-side swizzle (row&7 == l31&7 everywhere)

    // staging addresses: linear LDS dest, inverse-swizzled global source (R4)
    const unsigned char* kS = (const unsigned char*)Kp
        + ((t * 16) ^ (((t >> 5) & 7) << 4));                 // + kt*32768 + k*4096
    const unsigned char* vS = (const unsigned char*)Vp
        + (size_t)(t >> 3) * 4608
        + (((t & 7) * 16) ^ (((t >> 3) & 7) << 4));           // + kt*128 + k*147456
    unsigned char* kD = Ks + t * 16;                          // + k*4096
    unsigned char* vD = Vs + t * 16;                          // + k*4096

    // Q fragments in registers: rows qt*64 + qb*32 + l31, A-frag k = h*8+j
    bf16x8 qf[16];
    {
        const unsigned short* qp = Qp + (size_t)(qt * 64 + qb * 32 + l31) * CH + h * 8;
#pragma unroll
        for (int ks = 0; ks < 16; ++ks)
            qf[ks] = *(const bf16x8*)(qp + ks * 16);
    }

    f16v acc_o[4];
#pragma unroll
    for (int c = 0; c < 4; ++c)
#pragma unroll
        for (int r = 0; r < 16; ++r) acc_o[c][r] = 0.f;
    float l_acc[16];
#pragma unroll
    for (int r = 0; r < 16; ++r) l_acc[r] = 0.f;

    // prologue: issue K(0) then V(0); asm sep pins issue order for vmcnt math
#pragma unroll
    for (int k = 0; k < 8; ++k)
        __builtin_amdgcn_global_load_lds(
            (const unsigned int*)(kS + k * 4096),
            (unsigned int*)(kD + k * 4096), 16, 0, 0);
    asm volatile("" ::: "memory");
#pragma unroll
    for (int k = 0; k < 8; ++k)
        __builtin_amdgcn_global_load_lds(
            (const unsigned int*)(vS + (size_t)k * 147456),
            (unsigned int*)(vD + k * 4096), 16, 0, 0);

    for (int kt = 0; kt < 36; ++kt) {
        // (1) drain K(kt); V(kt)'s 8 stay in flight
        asm volatile("s_waitcnt vmcnt(8)" ::: "memory");
        __builtin_amdgcn_s_barrier();            // (2) B1: K(kt) visible
        asm volatile("" ::: "memory");

        // (3) QK^T: S[qb*32..+32][kb*32..+32], 16 k-steps
        f16v accs;
#pragma unroll
        for (int r = 0; r < 16; ++r) accs[r] = 0.f;
        const unsigned char* krow = Ks + ((kb * 32 + l31) << 9);
#pragma unroll
        for (int ks = 0; ks < 16; ++ks) {
            bf16x8 kf = *(const bf16x8*)(krow + ((ks * 32 + h * 16) ^ rxor));
            accs = __builtin_amdgcn_mfma_f32_32x32x16_bf16(qf[ks], kf, accs, 0, 0, 0);
        }
        // exp, partial row-sums, P write (C-layout row=(r&3)+8*(r>>2)+4h)
#pragma unroll
        for (int r = 0; r < 16; ++r) {
            float pe = __expf(accs[r] * (1.0f / 256.0f));
            l_acc[r] += pe;
            int row = (r & 3) + 8 * (r >> 2) + 4 * h;   // q within qb*32
            int q = qb * 32 + row;
            *(__bf16*)(Pb + q * 128 + ((kb * 64 + l31 * 2) ^ ((row & 7) << 4))) = (__bf16)pe;
        }
        // (4) drain V(kt) (hidden under QK^T) + P-writes
        asm volatile("s_waitcnt vmcnt(0) lgkmcnt(0)" ::: "memory");
        __builtin_amdgcn_s_barrier();            // (5) B2: P+V visible; K free
        asm volatile("" ::: "memory");

        // (6) issue K(kt+1): K readers done at B2
        if (kt < 35) {
            const unsigned char* ksn = kS + (size_t)(kt + 1) * 32768;
#pragma unroll
            for (int k = 0; k < 8; ++k)
                __builtin_amdgcn_global_load_lds(
                    (const unsigned int*)(ksn + k * 4096),
                    (unsigned int*)(kD + k * 4096), 16, 0, 0);
            asm volatile("" ::: "memory");
        }

        // (7) PV: O[qb*32..+32][chh*128..+128]
#pragma unroll
        for (int ks2 = 0; ks2 < 4; ++ks2) {
            bf16x8 pf = *(const bf16x8*)(Pb + ((qb * 32 + l31) << 7)
                                       + ((ks2 * 32 + h * 16) ^ rxor));
#pragma unroll
            for (int chb = 0; chb < 4; ++chb) {
                int ch = chh * 128 + chb * 32 + l31;
                bf16x8 vf = *(const bf16x8*)(Vs + (ch << 7)
                                           + ((ks2 * 32 + h * 16) ^ rxor));
                acc_o[chb] = __builtin_amdgcn_mfma_f32_32x32x16_bf16(pf, vf, acc_o[chb], 0, 0, 0);
            }
        }

        __builtin_amdgcn_s_barrier();            // (8) B0: V/P readers done
        asm volatile("" ::: "memory");

        // (9) issue V(kt+1)
        if (kt < 35) {
            const unsigned char* vsn = vS + (size_t)(kt + 1) * 128;
#pragma unroll
            for (int k = 0; k < 8; ++k)
                __builtin_amdgcn_global_load_lds(
                    (const unsigned int*)(vsn + (size_t)k * 147456),
                    (unsigned int*)(vD + k * 4096), 16, 0, 0);
            asm volatile("" ::: "memory");
        }
    }

    // ---- row-sum finalize: reduce over the 32 key-lanes (within each half)
#pragma unroll
    for (int r = 0; r < 16; ++r) {
        float rs = l_acc[r];
        rs += __shfl_xor(rs, 1, 64);
        rs += __shfl_xor(rs, 2, 64);
        rs += __shfl_xor(rs, 4, 64);
        rs += __shfl_xor(rs, 8, 64);
        rs += __shfl_xor(rs, 16, 64);
        l_acc[r] = rs;
    }
    if (l31 == 0) {   // lanes 0 and 32 publish their half's 16 rows
#pragma unroll
        for (int r = 0; r < 16; ++r) {
            int row = (r & 3) + 8 * (r >> 2) + 4 * h;
            Ls[w * 32 + row] = l_acc[r];
        }
    }
    __syncthreads();   // Ls visible; also fences last PV reads before Ot reuse
    float l_tot[16];
#pragma unroll
    for (int r = 0; r < 16; ++r) {
        int row = (r & 3) + 8 * (r >> 2) + 4 * h;
        l_tot[r] = Ls[w * 32 + row] + Ls[(w ^ 1) * 32 + row];  // kb0 + kb1
    }

    // ---- epilogue: normalize, swizzled fp32 transpose, coalesced stores
    float* Ot = (float*)lds;   // [256 ch][64 q] f32, dword-XOR ((c&7)<<2)
#pragma unroll
    for (int chb = 0; chb < 4; ++chb) {
        int c = chh * 128 + chb * 32 + l31;
        int cx = (c & 7) << 2;
#pragma unroll
        for (int rr = 0; rr < 4; ++rr) {
            f4v v4;
#pragma unroll
            for (int i = 0; i < 4; ++i)
                v4[i] = acc_o[chb][rr * 4 + i] / l_tot[rr * 4 + i];
            int q0 = qb * 32 + rr * 8 + h * 4;   // rows rr*8+{0..3}+4h consecutive
            *(f4v*)(Ot + c * 64 + (q0 ^ cx)) = v4;
        }
    }
    __syncthreads();
#pragma unroll
    for (int p = 0; p < 16; ++p) {
        int c = p * 16 + (t >> 4);
        int q = (t & 15) * 4;
        f4v v4 = *(const f4v*)(Ot + c * 64 + (q ^ ((c & 7) << 2)));
        *(f4v*)(Op + (size_t)c * NTOK + qt * 64 + q) = v4;
    }
}

// ---------------------------------------------------------------------------
extern "C" void kernel_launch(void* const* d_in, const int* in_sizes, int n_in,
                              void* d_out, int out_size, void* d_ws, size_t ws_size,
                              hipStream_t stream) {
    (void)in_sizes; (void)n_in; (void)out_size; (void)ws_size;
    const float* feaL  = (const float*)d_in[0];
    const float* feaR  = (const float*)d_in[1];
    const float* Wq    = (const float*)d_in[2];
    const float* bq    = (const float*)d_in[3];
    const float* gq    = (const float*)d_in[4];
    const float* betaq = (const float*)d_in[5];
    const float* mq    = (const float*)d_in[6];
    const float* vq    = (const float*)d_in[7];
    const float* Wk    = (const float*)d_in[8];
    const float* bk    = (const float*)d_in[9];
    const float* gk    = (const float*)d_in[10];
    const float* betak = (const float*)d_in[11];
    const float* mk    = (const float*)d_in[12];
    const float* vk    = (const float*)d_in[13];

    // workspace (bf16): XT/VT alias 16*MATSZ (18.9MB) | Y 32*MATSZ (37.7MB)
    unsigned short* XT = (unsigned short*)d_ws;   // reused as VT after proj
    unsigned short* VT = XT;
    unsigned short* Yb = XT + (size_t)16 * MATSZ;
    float* out = (float*)d_out;   // fp32: reference output dtype

    dim3 blk(256);
    // XT[s][b][pos][c] = fea[b][c][pos]
    tpose_k<<<dim3(144, 16), blk, 0, stream>>>(feaL, feaR, XT, 256, 2304);
    proj_k<<<dim3(144, 32), blk, 0, stream>>>(XT, Wq, Wk, bq, bk, gq, gk,
                                              betaq, betak, mq, mk, vq, vk, Yb);
    // VT[s][b][c][n] = fea_flat[n*256+c]
    tpose_k<<<dim3(144, 16), blk, 0, stream>>>(feaL, feaR, VT, 2304, 256);
    attn_k<<<dim3(576), blk, 0, stream>>>(Yb, VT, out);
}

// Round 11
// 310.850 us; speedup vs baseline: 1.8149x; 1.0337x over previous
//
#include <hip/hip_runtime.h>

#define CH    256
#define NTOK  2304
#define MATSZ (CH * NTOK)   // 589824 elements per (b, matrix)

typedef __bf16 bf16x8 __attribute__((ext_vector_type(8)));
typedef float  f4v    __attribute__((ext_vector_type(4)));
typedef float  f16v   __attribute__((ext_vector_type(16)));
typedef unsigned int u32x4 __attribute__((ext_vector_type(4)));

__device__ __forceinline__ unsigned short f2bf(float f) {
    union { float f; unsigned int i; } c;
    c.f = f;
    unsigned int x = c.i;
    x += 0x7fffu + ((x >> 16) & 1u);   // round-to-nearest-even
    return (unsigned short)(x >> 16);
}

__device__ __forceinline__ bf16x8 cvt8(const float* p) {
    union { bf16x8 v; unsigned short s[8]; } u;
#pragma unroll
    for (int i = 0; i < 8; ++i) u.s[i] = f2bf(p[i]);
    return u.v;
}

// ---------------------------------------------------------------------------
// 64x64-tiled transpose + fp32->bf16.
// R11: pad 72 -> 65. Old stride 72 shorts = 36 dwords = 4 (mod 32): the
// read phase tile[col][crow] put 64 lanes on 8 banks (8-way, ~5.7x cost,
// m136) for all 16 iterations. Odd stride 65: bank = ((col*65+crow)>>1)%32
// walks all 32 banks -> 2 lanes/bank = free. Scalar b16 accesses only, so
// no vector-alignment hazard. Addressing logic unchanged.
// ---------------------------------------------------------------------------
__global__ __launch_bounds__(256) void tpose_k(
    const float* __restrict__ inL,
    const float* __restrict__ inR,
    unsigned short* __restrict__ out, int R, int Ccols)
{
    __shared__ unsigned short tile[64][65];
    int mat = blockIdx.y;
    const float* in = (mat >= 8 ? inR : inL) + (size_t)(mat & 7) * MATSZ;
    unsigned short* o = out + (size_t)mat * MATSZ;
    int tC = Ccols >> 6;
    int r0 = (blockIdx.x / tC) << 6;
    int c0 = (blockIdx.x % tC) << 6;
    int t = threadIdx.x;
    int col = t & 63, rs = t >> 6;
#pragma unroll
    for (int i = 0; i < 16; ++i) {
        int row = rs + i * 4;
        tile[row][col] = f2bf(in[(size_t)(r0 + row) * Ccols + c0 + col]);
    }
    __syncthreads();
#pragma unroll
    for (int i = 0; i < 16; ++i) {
        int crow = rs + i * 4;
        o[(size_t)(c0 + crow) * R + r0 + col] = tile[col][crow];
    }
}

// ---------------------------------------------------------------------------
// Projection. R11: Xs [64][264] padded layout -> linear [64 pos][512B] with
// the R2/R4 HW-verified XOR swizzle (same 64x512B shape as attn's Ks, same
// maps). Old staging: 16B writes at row stride 132 dwords = 4 (mod 32) with
// the 4 same-row lanes at bank-identical cq offsets -> ~8 lanes per 4-bank
// group x8 iters. New: writes lane-linear (t*16, conflict-free); frag reads
// (kc*64+quad*16)^((row&7)<<4) -> 8 distinct 16B slots / 16-lane group.
// Staging write map (byte-identical to attn Ks, R2-verified): flat
// f = k*4096 + t*16; row = k*8+(t>>5); dst = Xs + (t*16 ^ ((t>>5&7)<<4)).
// MFMA compute / W loads / epilogue unchanged (HW-verified R5/R6).
// ---------------------------------------------------------------------------
__global__ __launch_bounds__(256, 2) void proj_k(
    const unsigned short* __restrict__ XT,   // [2][8][2304][256] bf16
    const float* __restrict__ Wq_, const float* __restrict__ Wk_,
    const float* __restrict__ bq_, const float* __restrict__ bk_,
    const float* __restrict__ gq_, const float* __restrict__ gk_,
    const float* __restrict__ beq_, const float* __restrict__ bek_,
    const float* __restrict__ mq_, const float* __restrict__ mk_,
    const float* __restrict__ vq_, const float* __restrict__ vk_,
    unsigned short* __restrict__ Yout)       // [4][8][MATSZ] bf16
{
    __shared__ __align__(16) unsigned char Xs[32768];   // 64 pos x 512B, XOR
    int pb = blockIdx.y;
    int p = pb >> 3, b = pb & 7;
    int s = p & 1, br = p >> 1;
    const unsigned short* X = XT + (size_t)(s * 8 + b) * MATSZ;
    const float* W  = br ? Wk_ : Wq_;
    const float* bb = br ? bk_ : bq_;
    const float* gg = br ? gk_ : gq_;
    const float* be = br ? bek_ : beq_;
    const float* mm = br ? mk_ : mq_;
    const float* vv = br ? vk_ : vq_;
    unsigned short* Yo = Yout + (size_t)pb * MATSZ;

    int ot = blockIdx.x & 3, pt = blockIdx.x >> 2;
    int o0 = ot * 64, pos0 = pt * 64;
    int t = threadIdx.x;
    int w = t >> 6, lane = t & 63;
    int l15 = lane & 15, quad = lane >> 4;
    int rxp = (l15 & 7) << 4;    // read-side swizzle (row&7 == l15&7)

    {   // stage XT tile: 64 pos-rows x 256 c, linear+XOR (R2-verified map)
        const unsigned short* src = X + (size_t)(pos0 + (t >> 5)) * CH + (t & 31) * 8;
        unsigned char* dst = Xs + ((t * 16) ^ (((t >> 5) & 7) << 4));
#pragma unroll
        for (int k = 0; k < 8; ++k)
            *(u32x4*)(dst + k * 4096) = *(const u32x4*)(src + (size_t)k * 8 * CH);
    }
    bf16x8 wf[8];
    {
        const float* wp = W + (size_t)(o0 + w * 16 + l15) * CH + quad * 8;
#pragma unroll
        for (int kc = 0; kc < 8; ++kc)
            wf[kc] = cvt8(wp + kc * 32);
    }
    __syncthreads();

    f4v zero4 = {0.f, 0.f, 0.f, 0.f};
    f4v acc[4] = {zero4, zero4, zero4, zero4};
#pragma unroll
    for (int kc = 0; kc < 8; ++kc) {
#pragma unroll
        for (int ct = 0; ct < 4; ++ct) {
            int row = ct * 16 + l15;
            bf16x8 xb = *(const bf16x8*)(Xs + (row << 9)
                                       + (((kc << 6) + (quad << 4)) ^ rxp));
            acc[ct] = __builtin_amdgcn_mfma_f32_16x16x32_bf16(wf[kc], xb, acc[ct], 0, 0, 0);
        }
    }
#pragma unroll
    for (int r = 0; r < 4; ++r) {
        int o = o0 + w * 16 + quad * 4 + r;
        float scale = gg[o] * rsqrtf(vv[o] + 1e-5f);
        float shift = (bb[o] - mm[o]) * scale + be[o];
#pragma unroll
        for (int ct = 0; ct < 4; ++ct) {
            float val = acc[ct][r] * scale + shift;
            Yo[(size_t)o * NTOK + pos0 + ct * 16 + l15] = f2bf(val);
        }
    }
}

// ---------------------------------------------------------------------------
// Fused attention — UNCHANGED from R10 (verified 165us): R4 32x32x16 compute
// + phase-shifted glld issue + counted vmcnt (T3/T4). See R10 notes.
// ---------------------------------------------------------------------------
__global__ __launch_bounds__(256, 2) void attn_k(
    const unsigned short* __restrict__ Y,    // [4][8][MATSZ] projections bf16
    const unsigned short* __restrict__ VT,   // [2][8][256][2304] bf16
    float* __restrict__ out)                 // [2][8][MATSZ] fp32
{
    __shared__ __align__(16) unsigned char lds[74240];
    unsigned char* Ks = lds;                    // 32768
    unsigned char* Vs = lds + 32768;            // 32768
    unsigned char* Pb = lds + 65536;            // 8192
    float*         Ls = (float*)(lds + 73728);  // [4][32] f32

    int bid = blockIdx.x;
    int wg = (bid & 7) * 72 + (bid >> 3);   // XCD swizzle (576 = 8*72, bijective)
    int qt = wg % 36;
    int ab = wg / 36;
    int a = ab >> 3, b = ab & 7;
    const unsigned short* Qp = Y + (size_t)(a * 8 + b) * MATSZ;        // q(l)/q(r)
    const unsigned short* Kp = Y + (size_t)((3 - a) * 8 + b) * MATSZ;  // k(r)/k(l)
    const unsigned short* Vp = VT + (size_t)((1 - a) * 8 + b) * MATSZ;
    float* Op = out + (size_t)ab * MATSZ;

    int t = threadIdx.x;
    int w = t >> 6, lane = t & 63;
    int l31 = lane & 31, h = lane >> 5;
    int qb = w >> 1;             // q-block (QK^T and PV)
    int kb = w & 1;              // key-block (QK^T)
    int chh = w & 1;             // channel-half (PV)
    int rxor = (l31 & 7) << 4;   // read-side swizzle (row&7 == l31&7 everywhere)

    // staging addresses: linear LDS dest, inverse-swizzled global source (R4)
    const unsigned char* kS = (const unsigned char*)Kp
        + ((t * 16) ^ (((t >> 5) & 7) << 4));                 // + kt*32768 + k*4096
    const unsigned char* vS = (const unsigned char*)Vp
        + (size_t)(t >> 3) * 4608
        + (((t & 7) * 16) ^ (((t >> 3) & 7) << 4));           // + kt*128 + k*147456
    unsigned char* kD = Ks + t * 16;                          // + k*4096
    unsigned char* vD = Vs + t * 16;                          // + k*4096

    // Q fragments in registers: rows qt*64 + qb*32 + l31, A-frag k = h*8+j
    bf16x8 qf[16];
    {
        const unsigned short* qp = Qp + (size_t)(qt * 64 + qb * 32 + l31) * CH + h * 8;
#pragma unroll
        for (int ks = 0; ks < 16; ++ks)
            qf[ks] = *(const bf16x8*)(qp + ks * 16);
    }

    f16v acc_o[4];
#pragma unroll
    for (int c = 0; c < 4; ++c)
#pragma unroll
        for (int r = 0; r < 16; ++r) acc_o[c][r] = 0.f;
    float l_acc[16];
#pragma unroll
    for (int r = 0; r < 16; ++r) l_acc[r] = 0.f;

    // prologue: issue K(0) then V(0); asm sep pins issue order for vmcnt math
#pragma unroll
    for (int k = 0; k < 8; ++k)
        __builtin_amdgcn_global_load_lds(
            (const unsigned int*)(kS + k * 4096),
            (unsigned int*)(kD + k * 4096), 16, 0, 0);
    asm volatile("" ::: "memory");
#pragma unroll
    for (int k = 0; k < 8; ++k)
        __builtin_amdgcn_global_load_lds(
            (const unsigned int*)(vS + (size_t)k * 147456),
            (unsigned int*)(vD + k * 4096), 16, 0, 0);

    for (int kt = 0; kt < 36; ++kt) {
        // (1) drain K(kt); V(kt)'s 8 stay in flight
        asm volatile("s_waitcnt vmcnt(8)" ::: "memory");
        __builtin_amdgcn_s_barrier();            // (2) B1: K(kt) visible
        asm volatile("" ::: "memory");

        // (3) QK^T: S[qb*32..+32][kb*32..+32], 16 k-steps
        f16v accs;
#pragma unroll
        for (int r = 0; r < 16; ++r) accs[r] = 0.f;
        const unsigned char* krow = Ks + ((kb * 32 + l31) << 9);
#pragma unroll
        for (int ks = 0; ks < 16; ++ks) {
            bf16x8 kf = *(const bf16x8*)(krow + ((ks * 32 + h * 16) ^ rxor));
            accs = __builtin_amdgcn_mfma_f32_32x32x16_bf16(qf[ks], kf, accs, 0, 0, 0);
        }
        // exp, partial row-sums, P write (C-layout row=(r&3)+8*(r>>2)+4h)
#pragma unroll
        for (int r = 0; r < 16; ++r) {
            float pe = __expf(accs[r] * (1.0f / 256.0f));
            l_acc[r] += pe;
            int row = (r & 3) + 8 * (r >> 2) + 4 * h;   // q within qb*32
            int q = qb * 32 + row;
            *(__bf16*)(Pb + q * 128 + ((kb * 64 + l31 * 2) ^ ((row & 7) << 4))) = (__bf16)pe;
        }
        // (4) drain V(kt) (hidden under QK^T) + P-writes
        asm volatile("s_waitcnt vmcnt(0) lgkmcnt(0)" ::: "memory");
        __builtin_amdgcn_s_barrier();            // (5) B2: P+V visible; K free
        asm volatile("" ::: "memory");

        // (6) issue K(kt+1): K readers done at B2
        if (kt < 35) {
            const unsigned char* ksn = kS + (size_t)(kt + 1) * 32768;
#pragma unroll
            for (int k = 0; k < 8; ++k)
                __builtin_amdgcn_global_load_lds(
                    (const unsigned int*)(ksn + k * 4096),
                    (unsigned int*)(kD + k * 4096), 16, 0, 0);
            asm volatile("" ::: "memory");
        }

        // (7) PV: O[qb*32..+32][chh*128..+128]
#pragma unroll
        for (int ks2 = 0; ks2 < 4; ++ks2) {
            bf16x8 pf = *(const bf16x8*)(Pb + ((qb * 32 + l31) << 7)
                                       + ((ks2 * 32 + h * 16) ^ rxor));
#pragma unroll
            for (int chb = 0; chb < 4; ++chb) {
                int ch = chh * 128 + chb * 32 + l31;
                bf16x8 vf = *(const bf16x8*)(Vs + (ch << 7)
                                           + ((ks2 * 32 + h * 16) ^ rxor));
                acc_o[chb] = __builtin_amdgcn_mfma_f32_32x32x16_bf16(pf, vf, acc_o[chb], 0, 0, 0);
            }
        }

        __builtin_amdgcn_s_barrier();            // (8) B0: V/P readers done
        asm volatile("" ::: "memory");

        // (9) issue V(kt+1)
        if (kt < 35) {
            const unsigned char* vsn = vS + (size_t)(kt + 1) * 128;
#pragma unroll
            for (int k = 0; k < 8; ++k)
                __builtin_amdgcn_global_load_lds(
                    (const unsigned int*)(vsn + (size_t)k * 147456),
                    (unsigned int*)(vD + k * 4096), 16, 0, 0);
            asm volatile("" ::: "memory");
        }
    }

    // ---- row-sum finalize: reduce over the 32 key-lanes (within each half)
#pragma unroll
    for (int r = 0; r < 16; ++r) {
        float rs = l_acc[r];
        rs += __shfl_xor(rs, 1, 64);
        rs += __shfl_xor(rs, 2, 64);
        rs += __shfl_xor(rs, 4, 64);
        rs += __shfl_xor(rs, 8, 64);
        rs += __shfl_xor(rs, 16, 64);
        l_acc[r] = rs;
    }
    if (l31 == 0) {   // lanes 0 and 32 publish their half's 16 rows
#pragma unroll
        for (int r = 0; r < 16; ++r) {
            int row = (r & 3) + 8 * (r >> 2) + 4 * h;
            Ls[w * 32 + row] = l_acc[r];
        }
    }
    __syncthreads();   // Ls visible; also fences last PV reads before Ot reuse
    float l_tot[16];
#pragma unroll
    for (int r = 0; r < 16; ++r) {
        int row = (r & 3) + 8 * (r >> 2) + 4 * h;
        l_tot[r] = Ls[w * 32 + row] + Ls[(w ^ 1) * 32 + row];  // kb0 + kb1
    }

    // ---- epilogue: normalize, swizzled fp32 transpose, coalesced stores
    float* Ot = (float*)lds;   // [256 ch][64 q] f32, dword-XOR ((c&7)<<2)
#pragma unroll
    for (int chb = 0; chb < 4; ++chb) {
        int c = chh * 128 + chb * 32 + l31;
        int cx = (c & 7) << 2;
#pragma unroll
        for (int rr = 0; rr < 4; ++rr) {
            f4v v4;
#pragma unroll
            for (int i = 0; i < 4; ++i)
                v4[i] = acc_o[chb][rr * 4 + i] / l_tot[rr * 4 + i];
            int q0 = qb * 32 + rr * 8 + h * 4;   // rows rr*8+{0..3}+4h consecutive
            *(f4v*)(Ot + c * 64 + (q0 ^ cx)) = v4;
        }
    }
    __syncthreads();
#pragma unroll
    for (int p = 0; p < 16; ++p) {
        int c = p * 16 + (t >> 4);
        int q = (t & 15) * 4;
        f4v v4 = *(const f4v*)(Ot + c * 64 + (q ^ ((c & 7) << 2)));
        *(f4v*)(Op + (size_t)c * NTOK + qt * 64 + q) = v4;
    }
}

// ---------------------------------------------------------------------------
extern "C" void kernel_launch(void* const* d_in, const int* in_sizes, int n_in,
                              void* d_out, int out_size, void* d_ws, size_t ws_size,
                              hipStream_t stream) {
    (void)in_sizes; (void)n_in; (void)out_size; (void)ws_size;
    const float* feaL  = (const float*)d_in[0];
    const float* feaR  = (const float*)d_in[1];
    const float* Wq    = (const float*)d_in[2];
    const float* bq    = (const float*)d_in[3];
    const float* gq    = (const float*)d_in[4];
    const float* betaq = (const float*)d_in[5];
    const float* mq    = (const float*)d_in[6];
    const float* vq    = (const float*)d_in[7];
    const float* Wk    = (const float*)d_in[8];
    const float* bk    = (const float*)d_in[9];
    const float* gk    = (const float*)d_in[10];
    const float* betak = (const float*)d_in[11];
    const float* mk    = (const float*)d_in[12];
    const float* vk    = (const float*)d_in[13];

    // workspace (bf16): XT/VT alias 16*MATSZ (18.9MB) | Y 32*MATSZ (37.7MB)
    unsigned short* XT = (unsigned short*)d_ws;   // reused as VT after proj
    unsigned short* VT = XT;
    unsigned short* Yb = XT + (size_t)16 * MATSZ;
    float* out = (float*)d_out;   // fp32: reference output dtype

    dim3 blk(256);
    // XT[s][b][pos][c] = fea[b][c][pos]
    tpose_k<<<dim3(144, 16), blk, 0, stream>>>(feaL, feaR, XT, 256, 2304);
    proj_k<<<dim3(144, 32), blk, 0, stream>>>(XT, Wq, Wk, bq, bk, gq, gk,
                                              betaq, betak, mq, mk, vq, vk, Yb);
    // VT[s][b][c][n] = fea_flat[n*256+c]
    tpose_k<<<dim3(144, 16), blk, 0, stream>>>(feaL, feaR, VT, 2304, 256);
    attn_k<<<dim3(576), blk, 0, stream>>>(Yb, VT, out);
}

// Round 13
// 299.038 us; speedup vs baseline: 1.8866x; 1.0395x over previous
//
#include <hip/hip_runtime.h>

#define CH    256
#define NTOK  2304
#define MATSZ (CH * NTOK)   // 589824 elements per (b, matrix)

typedef __bf16 bf16x8 __attribute__((ext_vector_type(8)));
typedef float  f4v    __attribute__((ext_vector_type(4)));
typedef float  f16v   __attribute__((ext_vector_type(16)));
typedef unsigned int u32x4 __attribute__((ext_vector_type(4)));

__device__ __forceinline__ unsigned short f2bf(float f) {
    union { float f; unsigned int i; } c;
    c.f = f;
    unsigned int x = c.i;
    x += 0x7fffu + ((x >> 16) & 1u);   // round-to-nearest-even
    return (unsigned short)(x >> 16);
}

// ---------------------------------------------------------------------------
// 64x64-tiled transpose + fp32->bf16 (tile pad 65 — R11 verified) PLUS
// R12: blockIdx.y == 16 blocks (first launch only) run W/BN pre-fold:
//   Wbf[br][o][c] = bf16( W[o][c] * scale[o] ),  scale = g*rsqrt(v+eps)
//   bias2[br][o]  = (b-m)*scale + beta
// stored in d_out-as-scratch (proj reads it BEFORE attn overwrites out;
// same-stream ordering makes this safe; no workspace-size risk).
// ---------------------------------------------------------------------------
__global__ __launch_bounds__(256) void tpose_k(
    const float* __restrict__ inL,
    const float* __restrict__ inR,
    unsigned short* __restrict__ out, int R, int Ccols,
    const float* __restrict__ Wq_, const float* __restrict__ Wk_,
    const float* __restrict__ bq_, const float* __restrict__ bk_,
    const float* __restrict__ gq_, const float* __restrict__ gk_,
    const float* __restrict__ beq_, const float* __restrict__ bek_,
    const float* __restrict__ mq_, const float* __restrict__ mk_,
    const float* __restrict__ vq_, const float* __restrict__ vk_,
    unsigned short* __restrict__ Wbf, float* __restrict__ bias2)
{
    if (blockIdx.y == 16) {   // W/BN pre-fold (144 blocks x 256 thr x 4 elems)
        int i0 = ((int)blockIdx.x * 256 + (int)threadIdx.x) * 4;
#pragma unroll
        for (int j = 0; j < 4; ++j) {
            int i = i0 + j;
            if (i < 131072) {                       // 2 * 256 * 256
                int br = i >> 16, oc = i & 65535, o = oc >> 8;
                float g = br ? gk_[o] : gq_[o];
                float v = br ? vk_[o] : vq_[o];
                float scale = g * rsqrtf(v + 1e-5f);
                float wv = (br ? Wk_ : Wq_)[oc];
                Wbf[i] = f2bf(wv * scale);
            }
        }
        int ib = (int)blockIdx.x * 256 + (int)threadIdx.x;
        if (ib < 512) {
            int br = ib >> 8, o = ib & 255;
            float g = br ? gk_[o] : gq_[o];
            float v = br ? vk_[o] : vq_[o];
            float scale = g * rsqrtf(v + 1e-5f);
            float bb = br ? bk_[o] : bq_[o];
            float mm = br ? mk_[o] : mq_[o];
            float be = br ? bek_[o] : beq_[o];
            bias2[ib] = (bb - mm) * scale + be;
        }
        return;
    }

    __shared__ unsigned short tile[64][65];
    int mat = blockIdx.y;
    const float* in = (mat >= 8 ? inR : inL) + (size_t)(mat & 7) * MATSZ;
    unsigned short* o = out + (size_t)mat * MATSZ;
    int tC = Ccols >> 6;
    int r0 = (blockIdx.x / tC) << 6;
    int c0 = (blockIdx.x % tC) << 6;
    int t = threadIdx.x;
    int col = t & 63, rs = t >> 6;
#pragma unroll
    for (int i = 0; i < 16; ++i) {
        int row = rs + i * 4;
        tile[row][col] = f2bf(in[(size_t)(r0 + row) * Ccols + c0 + col]);
    }
    __syncthreads();
#pragma unroll
    for (int i = 0; i < 16; ++i) {
        int crow = rs + i * 4;
        o[(size_t)(c0 + crow) * R + r0 + col] = tile[col][crow];
    }
}

// ---------------------------------------------------------------------------
// Projection R12: W loaded as pre-folded bf16 (no per-block fp32 cvt — was
// ~256 VALU inst/thread, re-done 36x per W tile), BN epilogue collapsed to
// acc + bias2[o]. Xs staging/swizzle unchanged from R11 (verified).
// ---------------------------------------------------------------------------
__global__ __launch_bounds__(256, 2) void proj_k(
    const unsigned short* __restrict__ XT,   // [2][8][2304][256] bf16
    const unsigned short* __restrict__ Wbf,  // [2][256][256] bf16 pre-scaled
    const float* __restrict__ bias2,         // [2][256] fp32
    unsigned short* __restrict__ Yout)       // [4][8][MATSZ] bf16
{
    __shared__ __align__(16) unsigned char Xs[32768];   // 64 pos x 512B, XOR
    int pb = blockIdx.y;
    int p = pb >> 3, b = pb & 7;
    int s = p & 1, br = p >> 1;
    const unsigned short* X = XT + (size_t)(s * 8 + b) * MATSZ;
    unsigned short* Yo = Yout + (size_t)pb * MATSZ;

    int ot = blockIdx.x & 3, pt = blockIdx.x >> 2;
    int o0 = ot * 64, pos0 = pt * 64;
    int t = threadIdx.x;
    int w = t >> 6, lane = t & 63;
    int l15 = lane & 15, quad = lane >> 4;
    int rxp = (l15 & 7) << 4;    // read-side swizzle (row&7 == l15&7)

    {   // stage XT tile: 64 pos-rows x 256 c, linear+XOR (R2-verified map)
        const unsigned short* src = X + (size_t)(pos0 + (t >> 5)) * CH + (t & 31) * 8;
        unsigned char* dst = Xs + ((t * 16) ^ (((t >> 5) & 7) << 4));
#pragma unroll
        for (int k = 0; k < 8; ++k)
            *(u32x4*)(dst + k * 4096) = *(const u32x4*)(src + (size_t)k * 8 * CH);
    }
    bf16x8 wf[8];
    {
        const unsigned short* wp = Wbf + (size_t)br * 65536
                                 + (size_t)(o0 + w * 16 + l15) * CH + quad * 8;
#pragma unroll
        for (int kc = 0; kc < 8; ++kc)
            wf[kc] = *(const bf16x8*)(wp + kc * 32);
    }
    __syncthreads();

    f4v zero4 = {0.f, 0.f, 0.f, 0.f};
    f4v acc[4] = {zero4, zero4, zero4, zero4};
#pragma unroll
    for (int kc = 0; kc < 8; ++kc) {
#pragma unroll
        for (int ct = 0; ct < 4; ++ct) {
            int row = ct * 16 + l15;
            bf16x8 xb = *(const bf16x8*)(Xs + (row << 9)
                                       + (((kc << 6) + (quad << 4)) ^ rxp));
            acc[ct] = __builtin_amdgcn_mfma_f32_16x16x32_bf16(wf[kc], xb, acc[ct], 0, 0, 0);
        }
    }
#pragma unroll
    for (int r = 0; r < 4; ++r) {
        int o = o0 + w * 16 + quad * 4 + r;
        float shift = bias2[br * 256 + o];
#pragma unroll
        for (int ct = 0; ct < 4; ++ct) {
            float val = acc[ct][r] + shift;
            Yo[(size_t)o * NTOK + pos0 + ct * 16 + l15] = f2bf(val);
        }
    }
}

// ---------------------------------------------------------------------------
// Fused attention — UNCHANGED from R10/R11 (verified 164.6us): 32x32x16
// compute + phase-shifted glld issue + counted vmcnt (T3/T4).
// ---------------------------------------------------------------------------
__global__ __launch_bounds__(256, 2) void attn_k(
    const unsigned short* __restrict__ Y,    // [4][8][MATSZ] projections bf16
    const unsigned short* __restrict__ VT,   // [2][8][256][2304] bf16
    float* __restrict__ out)                 // [2][8][MATSZ] fp32
{
    __shared__ __align__(16) unsigned char lds[74240];
    unsigned char* Ks = lds;                    // 32768
    unsigned char* Vs = lds + 32768;            // 32768
    unsigned char* Pb = lds + 65536;            // 8192
    float*         Ls = (float*)(lds + 73728);  // [4][32] f32

    int bid = blockIdx.x;
    int wg = (bid & 7) * 72 + (bid >> 3);   // XCD swizzle (576 = 8*72, bijective)
    int qt = wg % 36;
    int ab = wg / 36;
    int a = ab >> 3, b = ab & 7;
    const unsigned short* Qp = Y + (size_t)(a * 8 + b) * MATSZ;        // q(l)/q(r)
    const unsigned short* Kp = Y + (size_t)((3 - a) * 8 + b) * MATSZ;  // k(r)/k(l)
    const unsigned short* Vp = VT + (size_t)((1 - a) * 8 + b) * MATSZ;
    float* Op = out + (size_t)ab * MATSZ;

    int t = threadIdx.x;
    int w = t >> 6, lane = t & 63;
    int l31 = lane & 31, h = lane >> 5;
    int qb = w >> 1;             // q-block (QK^T and PV)
    int kb = w & 1;              // key-block (QK^T)
    int chh = w & 1;             // channel-half (PV)
    int rxor = (l31 & 7) << 4;   // read-side swizzle (row&7 == l31&7 everywhere)

    // staging addresses: linear LDS dest, inverse-swizzled global source (R4)
    const unsigned char* kS = (const unsigned char*)Kp
        + ((t * 16) ^ (((t >> 5) & 7) << 4));                 // + kt*32768 + k*4096
    const unsigned char* vS = (const unsigned char*)Vp
        + (size_t)(t >> 3) * 4608
        + (((t & 7) * 16) ^ (((t >> 3) & 7) << 4));           // + kt*128 + k*147456
    unsigned char* kD = Ks + t * 16;                          // + k*4096
    unsigned char* vD = Vs + t * 16;                          // + k*4096

    // Q fragments in registers: rows qt*64 + qb*32 + l31, A-frag k = h*8+j
    bf16x8 qf[16];
    {
        const unsigned short* qp = Qp + (size_t)(qt * 64 + qb * 32 + l31) * CH + h * 8;
#pragma unroll
        for (int ks = 0; ks < 16; ++ks)
            qf[ks] = *(const bf16x8*)(qp + ks * 16);
    }

    f16v acc_o[4];
#pragma unroll
    for (int c = 0; c < 4; ++c)
#pragma unroll
        for (int r = 0; r < 16; ++r) acc_o[c][r] = 0.f;
    float l_acc[16];
#pragma unroll
    for (int r = 0; r < 16; ++r) l_acc[r] = 0.f;

    // prologue: issue K(0) then V(0); asm sep pins issue order for vmcnt math
#pragma unroll
    for (int k = 0; k < 8; ++k)
        __builtin_amdgcn_global_load_lds(
            (const unsigned int*)(kS + k * 4096),
            (unsigned int*)(kD + k * 4096), 16, 0, 0);
    asm volatile("" ::: "memory");
#pragma unroll
    for (int k = 0; k < 8; ++k)
        __builtin_amdgcn_global_load_lds(
            (const unsigned int*)(vS + (size_t)k * 147456),
            (unsigned int*)(vD + k * 4096), 16, 0, 0);

    for (int kt = 0; kt < 36; ++kt) {
        // (1) drain K(kt); V(kt)'s 8 stay in flight
        asm volatile("s_waitcnt vmcnt(8)" ::: "memory");
        __builtin_amdgcn_s_barrier();            // (2) B1: K(kt) visible
        asm volatile("" ::: "memory");

        // (3) QK^T: S[qb*32..+32][kb*32..+32], 16 k-steps
        f16v accs;
#pragma unroll
        for (int r = 0; r < 16; ++r) accs[r] = 0.f;
        const unsigned char* krow = Ks + ((kb * 32 + l31) << 9);
#pragma unroll
        for (int ks = 0; ks < 16; ++ks) {
            bf16x8 kf = *(const bf16x8*)(krow + ((ks * 32 + h * 16) ^ rxor));
            accs = __builtin_amdgcn_mfma_f32_32x32x16_bf16(qf[ks], kf, accs, 0, 0, 0);
        }
        // exp, partial row-sums, P write (C-layout row=(r&3)+8*(r>>2)+4h)
#pragma unroll
        for (int r = 0; r < 16; ++r) {
            float pe = __expf(accs[r] * (1.0f / 256.0f));
            l_acc[r] += pe;
            int row = (r & 3) + 8 * (r >> 2) + 4 * h;   // q within qb*32
            int q = qb * 32 + row;
            *(__bf16*)(Pb + q * 128 + ((kb * 64 + l31 * 2) ^ ((row & 7) << 4))) = (__bf16)pe;
        }
        // (4) drain V(kt) (hidden under QK^T) + P-writes
        asm volatile("s_waitcnt vmcnt(0) lgkmcnt(0)" ::: "memory");
        __builtin_amdgcn_s_barrier();            // (5) B2: P+V visible; K free
        asm volatile("" ::: "memory");

        // (6) issue K(kt+1): K readers done at B2
        if (kt < 35) {
            const unsigned char* ksn = kS + (size_t)(kt + 1) * 32768;
#pragma unroll
            for (int k = 0; k < 8; ++k)
                __builtin_amdgcn_global_load_lds(
                    (const unsigned int*)(ksn + k * 4096),
                    (unsigned int*)(kD + k * 4096), 16, 0, 0);
            asm volatile("" ::: "memory");
        }

        // (7) PV: O[qb*32..+32][chh*128..+128]
#pragma unroll
        for (int ks2 = 0; ks2 < 4; ++ks2) {
            bf16x8 pf = *(const bf16x8*)(Pb + ((qb * 32 + l31) << 7)
                                       + ((ks2 * 32 + h * 16) ^ rxor));
#pragma unroll
            for (int chb = 0; chb < 4; ++chb) {
                int ch = chh * 128 + chb * 32 + l31;
                bf16x8 vf = *(const bf16x8*)(Vs + (ch << 7)
                                           + ((ks2 * 32 + h * 16) ^ rxor));
                acc_o[chb] = __builtin_amdgcn_mfma_f32_32x32x16_bf16(pf, vf, acc_o[chb], 0, 0, 0);
            }
        }

        __builtin_amdgcn_s_barrier();            // (8) B0: V/P readers done
        asm volatile("" ::: "memory");

        // (9) issue V(kt+1)
        if (kt < 35) {
            const unsigned char* vsn = vS + (size_t)(kt + 1) * 128;
#pragma unroll
            for (int k = 0; k < 8; ++k)
                __builtin_amdgcn_global_load_lds(
                    (const unsigned int*)(vsn + (size_t)k * 147456),
                    (unsigned int*)(vD + k * 4096), 16, 0, 0);
            asm volatile("" ::: "memory");
        }
    }

    // ---- row-sum finalize: reduce over the 32 key-lanes (within each half)
#pragma unroll
    for (int r = 0; r < 16; ++r) {
        float rs = l_acc[r];
        rs += __shfl_xor(rs, 1, 64);
        rs += __shfl_xor(rs, 2, 64);
        rs += __shfl_xor(rs, 4, 64);
        rs += __shfl_xor(rs, 8, 64);
        rs += __shfl_xor(rs, 16, 64);
        l_acc[r] = rs;
    }
    if (l31 == 0) {   // lanes 0 and 32 publish their half's 16 rows
#pragma unroll
        for (int r = 0; r < 16; ++r) {
            int row = (r & 3) + 8 * (r >> 2) + 4 * h;
            Ls[w * 32 + row] = l_acc[r];
        }
    }
    __syncthreads();   // Ls visible; also fences last PV reads before Ot reuse
    float l_tot[16];
#pragma unroll
    for (int r = 0; r < 16; ++r) {
        int row = (r & 3) + 8 * (r >> 2) + 4 * h;
        l_tot[r] = Ls[w * 32 + row] + Ls[(w ^ 1) * 32 + row];  // kb0 + kb1
    }

    // ---- epilogue: normalize, swizzled fp32 transpose, coalesced stores
    float* Ot = (float*)lds;   // [256 ch][64 q] f32, dword-XOR ((c&7)<<2)
#pragma unroll
    for (int chb = 0; chb < 4; ++chb) {
        int c = chh * 128 + chb * 32 + l31;
        int cx = (c & 7) << 2;
#pragma unroll
        for (int rr = 0; rr < 4; ++rr) {
            f4v v4;
#pragma unroll
            for (int i = 0; i < 4; ++i)
                v4[i] = acc_o[chb][rr * 4 + i] / l_tot[rr * 4 + i];
            int q0 = qb * 32 + rr * 8 + h * 4;   // rows rr*8+{0..3}+4h consecutive
            *(f4v*)(Ot + c * 64 + (q0 ^ cx)) = v4;
        }
    }
    __syncthreads();
#pragma unroll
    for (int p = 0; p < 16; ++p) {
        int c = p * 16 + (t >> 4);
        int q = (t & 15) * 4;
        f4v v4 = *(const f4v*)(Ot + c * 64 + (q ^ ((c & 7) << 2)));
        *(f4v*)(Op + (size_t)c * NTOK + qt * 64 + q) = v4;
    }
}

// ---------------------------------------------------------------------------
extern "C" void kernel_launch(void* const* d_in, const int* in_sizes, int n_in,
                              void* d_out, int out_size, void* d_ws, size_t ws_size,
                              hipStream_t stream) {
    (void)in_sizes; (void)n_in; (void)out_size; (void)ws_size;
    const float* feaL  = (const float*)d_in[0];
    const float* feaR  = (const float*)d_in[1];
    const float* Wq    = (const float*)d_in[2];
    const float* bq    = (const float*)d_in[3];
    const float* gq    = (const float*)d_in[4];
    const float* betaq = (const float*)d_in[5];
    const float* mq    = (const float*)d_in[6];
    const float* vq    = (const float*)d_in[7];
    const float* Wk    = (const float*)d_in[8];
    const float* bk    = (const float*)d_in[9];
    const float* gk    = (const float*)d_in[10];
    const float* betak = (const float*)d_in[11];
    const float* mk    = (const float*)d_in[12];
    const float* vk    = (const float*)d_in[13];

    // workspace (bf16): XT/VT alias 16*MATSZ (18.9MB) | Y 32*MATSZ (37.7MB)
    unsigned short* XT = (unsigned short*)d_ws;   // reused as VT after proj
    unsigned short* VT = XT;
    unsigned short* Yb = XT + (size_t)16 * MATSZ;
    float* out = (float*)d_out;   // fp32: reference output dtype

    // d_out-as-scratch for pre-folded weights: written by tpose1's prep
    // blocks, read by proj, then fully overwritten by attn (stream-ordered).
    unsigned short* Wbf = (unsigned short*)d_out;          // [2][256][256] bf16
    float* bias2 = (float*)(Wbf + 131072);                 // [2][256] f32

    dim3 blk(256);
    // XT[s][b][pos][c] = fea[b][c][pos]; y==16 blocks do W/BN pre-fold
    tpose_k<<<dim3(144, 17), blk, 0, stream>>>(feaL, feaR, XT, 256, 2304,
                                               Wq, Wk, bq, bk, gq, gk,
                                               betaq, betak, mq, mk, vq, vk,
                                               Wbf, bias2);
    proj_k<<<dim3(144, 32), blk, 0, stream>>>(XT, Wbf, bias2, Yb);
    // VT[s][b][c][n] = fea_flat[n*256+c]
    tpose_k<<<dim3(144, 16), blk, 0, stream>>>(feaL, feaR, VT, 2304, 256,
                                               Wq, Wk, bq, bk, gq, gk,
                                               betaq, betak, mq, mk, vq, vk,
                                               Wbf, bias2);
    attn_k<<<dim3(576), blk, 0, stream>>>(Yb, VT, out);
}

// Round 15
// 296.870 us; speedup vs baseline: 1.9004x; 1.0073x over previous
//
#include <hip/hip_runtime.h>

#define CH    256
#define NTOK  2304
#define MATSZ (CH * NTOK)   // 589824 elements per (b, matrix)

typedef __bf16 bf16x8 __attribute__((ext_vector_type(8)));
typedef float  f4v    __attribute__((ext_vector_type(4)));
typedef float  f16v   __attribute__((ext_vector_type(16)));
typedef unsigned int u32x4 __attribute__((ext_vector_type(4)));

__device__ __forceinline__ unsigned short f2bf(float f) {
    union { float f; unsigned int i; } c;
    c.f = f;
    unsigned int x = c.i;
    x += 0x7fffu + ((x >> 16) & 1u);   // round-to-nearest-even
    return (unsigned short)(x >> 16);
}

// ---------------------------------------------------------------------------
// 64x64-tiled transpose + fp32->bf16 (tile pad 65 — R11 verified) PLUS
// blockIdx.y == 16 blocks (first launch only) run W/BN pre-fold (R12/R13
// verified): Wbf = bf16(W*scale), bias2 = (b-m)*scale+beta, in d_out-scratch.
// ---------------------------------------------------------------------------
__global__ __launch_bounds__(256) void tpose_k(
    const float* __restrict__ inL,
    const float* __restrict__ inR,
    unsigned short* __restrict__ out, int R, int Ccols,
    const float* __restrict__ Wq_, const float* __restrict__ Wk_,
    const float* __restrict__ bq_, const float* __restrict__ bk_,
    const float* __restrict__ gq_, const float* __restrict__ gk_,
    const float* __restrict__ beq_, const float* __restrict__ bek_,
    const float* __restrict__ mq_, const float* __restrict__ mk_,
    const float* __restrict__ vq_, const float* __restrict__ vk_,
    unsigned short* __restrict__ Wbf, float* __restrict__ bias2)
{
    if (blockIdx.y == 16) {   // W/BN pre-fold (144 blocks x 256 thr x 4 elems)
        int i0 = ((int)blockIdx.x * 256 + (int)threadIdx.x) * 4;
#pragma unroll
        for (int j = 0; j < 4; ++j) {
            int i = i0 + j;
            if (i < 131072) {                       // 2 * 256 * 256
                int br = i >> 16, oc = i & 65535, o = oc >> 8;
                float g = br ? gk_[o] : gq_[o];
                float v = br ? vk_[o] : vq_[o];
                float scale = g * rsqrtf(v + 1e-5f);
                float wv = (br ? Wk_ : Wq_)[oc];
                Wbf[i] = f2bf(wv * scale);
            }
        }
        int ib = (int)blockIdx.x * 256 + (int)threadIdx.x;
        if (ib < 512) {
            int br = ib >> 8, o = ib & 255;
            float g = br ? gk_[o] : gq_[o];
            float v = br ? vk_[o] : vq_[o];
            float scale = g * rsqrtf(v + 1e-5f);
            float bb = br ? bk_[o] : bq_[o];
            float mm = br ? mk_[o] : mq_[o];
            float be = br ? bek_[o] : beq_[o];
            bias2[ib] = (bb - mm) * scale + be;
        }
        return;
    }

    __shared__ unsigned short tile[64][65];
    int mat = blockIdx.y;
    const float* in = (mat >= 8 ? inR : inL) + (size_t)(mat & 7) * MATSZ;
    unsigned short* o = out + (size_t)mat * MATSZ;
    int tC = Ccols >> 6;
    int r0 = (blockIdx.x / tC) << 6;
    int c0 = (blockIdx.x % tC) << 6;
    int t = threadIdx.x;
    int col = t & 63, rs = t >> 6;
#pragma unroll
    for (int i = 0; i < 16; ++i) {
        int row = rs + i * 4;
        tile[row][col] = f2bf(in[(size_t)(r0 + row) * Ccols + c0 + col]);
    }
    __syncthreads();
#pragma unroll
    for (int i = 0; i < 16; ++i) {
        int crow = rs + i * 4;
        o[(size_t)(c0 + crow) * R + r0 + col] = tile[col][crow];
    }
}

// ---------------------------------------------------------------------------
// Projection R14: one block per X tile. Grid (36 pt, 16 sb). Each block
// stages its 64-pos x 256-ch X tile ONCE (R11/R13-verified map), then loops
// br x ot (8 passes): per pass, load W fragments (L2-hot, 0.25MB total
// broadcast) + the verified 16-MFMA inner loop + epilogue.
// Was: grid (144,32) — the same X tile staged by 8 different blocks
// (4 ot x 2 br) = 151MB X re-read; now 18.9MB (1x). Per-output arithmetic
// bitwise identical (same fragments, same MFMA order) -> absmax unchanged.
// ---------------------------------------------------------------------------
__global__ __launch_bounds__(256, 2) void proj_k(
    const unsigned short* __restrict__ XT,   // [2][8][2304][256] bf16
    const unsigned short* __restrict__ Wbf,  // [2][256][256] bf16 pre-scaled
    const float* __restrict__ bias2,         // [2][256] fp32
    unsigned short* __restrict__ Yout)       // [4][8][MATSZ] bf16
{
    __shared__ __align__(16) unsigned char Xs[32768];   // 64 pos x 512B, XOR
    int sb = blockIdx.y;                 // s*8 + b
    int s = sb >> 3, b = sb & 7;
    const unsigned short* X = XT + (size_t)sb * MATSZ;

    int pt = blockIdx.x;
    int pos0 = pt * 64;
    int t = threadIdx.x;
    int w = t >> 6, lane = t & 63;
    int l15 = lane & 15, quad = lane >> 4;
    int rxp = (l15 & 7) << 4;    // read-side swizzle (row&7 == l15&7)

    {   // stage XT tile once: 64 pos-rows x 256 c, linear+XOR (verified map)
        const unsigned short* src = X + (size_t)(pos0 + (t >> 5)) * CH + (t & 31) * 8;
        unsigned char* dst = Xs + ((t * 16) ^ (((t >> 5) & 7) << 4));
#pragma unroll
        for (int k = 0; k < 8; ++k)
            *(u32x4*)(dst + k * 4096) = *(const u32x4*)(src + (size_t)k * 8 * CH);
    }
    __syncthreads();

    f4v zero4 = {0.f, 0.f, 0.f, 0.f};
#pragma unroll 1
    for (int br = 0; br < 2; ++br) {
        unsigned short* Yo = Yout + (size_t)((br * 2 + s) * 8 + b) * MATSZ;
#pragma unroll 1
        for (int ot = 0; ot < 4; ++ot) {
            int o0 = ot * 64;
            bf16x8 wf[8];
            {
                const unsigned short* wp = Wbf + (size_t)br * 65536
                                         + (size_t)(o0 + w * 16 + l15) * CH + quad * 8;
#pragma unroll
                for (int kc = 0; kc < 8; ++kc)
                    wf[kc] = *(const bf16x8*)(wp + kc * 32);
            }
            f4v acc[4] = {zero4, zero4, zero4, zero4};
#pragma unroll
            for (int kc = 0; kc < 8; ++kc) {
#pragma unroll
                for (int ct = 0; ct < 4; ++ct) {
                    int row = ct * 16 + l15;
                    bf16x8 xb = *(const bf16x8*)(Xs + (row << 9)
                                               + (((kc << 6) + (quad << 4)) ^ rxp));
                    acc[ct] = __builtin_amdgcn_mfma_f32_16x16x32_bf16(wf[kc], xb, acc[ct], 0, 0, 0);
                }
            }
#pragma unroll
            for (int r = 0; r < 4; ++r) {
                int o = o0 + w * 16 + quad * 4 + r;
                float shift = bias2[br * 256 + o];
#pragma unroll
                for (int ct = 0; ct < 4; ++ct) {
                    float val = acc[ct][r] + shift;
                    Yo[(size_t)o * NTOK + pos0 + ct * 16 + l15] = f2bf(val);
                }
            }
        }
    }
}

// ---------------------------------------------------------------------------
// Fused attention — UNCHANGED from R10-R13 (verified 164.6-165.0us):
// 32x32x16 compute + phase-shifted glld issue + counted vmcnt (T3/T4).
// ---------------------------------------------------------------------------
__global__ __launch_bounds__(256, 2) void attn_k(
    const unsigned short* __restrict__ Y,    // [4][8][MATSZ] projections bf16
    const unsigned short* __restrict__ VT,   // [2][8][256][2304] bf16
    float* __restrict__ out)                 // [2][8][MATSZ] fp32
{
    __shared__ __align__(16) unsigned char lds[74240];
    unsigned char* Ks = lds;                    // 32768
    unsigned char* Vs = lds + 32768;            // 32768
    unsigned char* Pb = lds + 65536;            // 8192
    float*         Ls = (float*)(lds + 73728);  // [4][32] f32

    int bid = blockIdx.x;
    int wg = (bid & 7) * 72 + (bid >> 3);   // XCD swizzle (576 = 8*72, bijective)
    int qt = wg % 36;
    int ab = wg / 36;
    int a = ab >> 3, b = ab & 7;
    const unsigned short* Qp = Y + (size_t)(a * 8 + b) * MATSZ;        // q(l)/q(r)
    const unsigned short* Kp = Y + (size_t)((3 - a) * 8 + b) * MATSZ;  // k(r)/k(l)
    const unsigned short* Vp = VT + (size_t)((1 - a) * 8 + b) * MATSZ;
    float* Op = out + (size_t)ab * MATSZ;

    int t = threadIdx.x;
    int w = t >> 6, lane = t & 63;
    int l31 = lane & 31, h = lane >> 5;
    int qb = w >> 1;             // q-block (QK^T and PV)
    int kb = w & 1;              // key-block (QK^T)
    int chh = w & 1;             // channel-half (PV)
    int rxor = (l31 & 7) << 4;   // read-side swizzle (row&7 == l31&7 everywhere)

    // staging addresses: linear LDS dest, inverse-swizzled global source (R4)
    const unsigned char* kS = (const unsigned char*)Kp
        + ((t * 16) ^ (((t >> 5) & 7) << 4));                 // + kt*32768 + k*4096
    const unsigned char* vS = (const unsigned char*)Vp
        + (size_t)(t >> 3) * 4608
        + (((t & 7) * 16) ^ (((t >> 3) & 7) << 4));           // + kt*128 + k*147456
    unsigned char* kD = Ks + t * 16;                          // + k*4096
    unsigned char* vD = Vs + t * 16;                          // + k*4096

    // Q fragments in registers: rows qt*64 + qb*32 + l31, A-frag k = h*8+j
    bf16x8 qf[16];
    {
        const unsigned short* qp = Qp + (size_t)(qt * 64 + qb * 32 + l31) * CH + h * 8;
#pragma unroll
        for (int ks = 0; ks < 16; ++ks)
            qf[ks] = *(const bf16x8*)(qp + ks * 16);
    }

    f16v acc_o[4];
#pragma unroll
    for (int c = 0; c < 4; ++c)
#pragma unroll
        for (int r = 0; r < 16; ++r) acc_o[c][r] = 0.f;
    float l_acc[16];
#pragma unroll
    for (int r = 0; r < 16; ++r) l_acc[r] = 0.f;

    // prologue: issue K(0) then V(0); asm sep pins issue order for vmcnt math
#pragma unroll
    for (int k = 0; k < 8; ++k)
        __builtin_amdgcn_global_load_lds(
            (const unsigned int*)(kS + k * 4096),
            (unsigned int*)(kD + k * 4096), 16, 0, 0);
    asm volatile("" ::: "memory");
#pragma unroll
    for (int k = 0; k < 8; ++k)
        __builtin_amdgcn_global_load_lds(
            (const unsigned int*)(vS + (size_t)k * 147456),
            (unsigned int*)(vD + k * 4096), 16, 0, 0);

    for (int kt = 0; kt < 36; ++kt) {
        // (1) drain K(kt); V(kt)'s 8 stay in flight
        asm volatile("s_waitcnt vmcnt(8)" ::: "memory");
        __builtin_amdgcn_s_barrier();            // (2) B1: K(kt) visible
        asm volatile("" ::: "memory");

        // (3) QK^T: S[qb*32..+32][kb*32..+32], 16 k-steps
        f16v accs;
#pragma unroll
        for (int r = 0; r < 16; ++r) accs[r] = 0.f;
        const unsigned char* krow = Ks + ((kb * 32 + l31) << 9);
#pragma unroll
        for (int ks = 0; ks < 16; ++ks) {
            bf16x8 kf = *(const bf16x8*)(krow + ((ks * 32 + h * 16) ^ rxor));
            accs = __builtin_amdgcn_mfma_f32_32x32x16_bf16(qf[ks], kf, accs, 0, 0, 0);
        }
        // exp, partial row-sums, P write (C-layout row=(r&3)+8*(r>>2)+4h)
#pragma unroll
        for (int r = 0; r < 16; ++r) {
            float pe = __expf(accs[r] * (1.0f / 256.0f));
            l_acc[r] += pe;
            int row = (r & 3) + 8 * (r >> 2) + 4 * h;   // q within qb*32
            int q = qb * 32 + row;
            *(__bf16*)(Pb + q * 128 + ((kb * 64 + l31 * 2) ^ ((row & 7) << 4))) = (__bf16)pe;
        }
        // (4) drain V(kt) (hidden under QK^T) + P-writes
        asm volatile("s_waitcnt vmcnt(0) lgkmcnt(0)" ::: "memory");
        __builtin_amdgcn_s_barrier();            // (5) B2: P+V visible; K free
        asm volatile("" ::: "memory");

        // (6) issue K(kt+1): K readers done at B2
        if (kt < 35) {
            const unsigned char* ksn = kS + (size_t)(kt + 1) * 32768;
#pragma unroll
            for (int k = 0; k < 8; ++k)
                __builtin_amdgcn_global_load_lds(
                    (const unsigned int*)(ksn + k * 4096),
                    (unsigned int*)(kD + k * 4096), 16, 0, 0);
            asm volatile("" ::: "memory");
        }

        // (7) PV: O[qb*32..+32][chh*128..+128]
#pragma unroll
        for (int ks2 = 0; ks2 < 4; ++ks2) {
            bf16x8 pf = *(const bf16x8*)(Pb + ((qb * 32 + l31) << 7)
                                       + ((ks2 * 32 + h * 16) ^ rxor));
#pragma unroll
            for (int chb = 0; chb < 4; ++chb) {
                int ch = chh * 128 + chb * 32 + l31;
                bf16x8 vf = *(const bf16x8*)(Vs + (ch << 7)
                                           + ((ks2 * 32 + h * 16) ^ rxor));
                acc_o[chb] = __builtin_amdgcn_mfma_f32_32x32x16_bf16(pf, vf, acc_o[chb], 0, 0, 0);
            }
        }

        __builtin_amdgcn_s_barrier();            // (8) B0: V/P readers done
        asm volatile("" ::: "memory");

        // (9) issue V(kt+1)
        if (kt < 35) {
            const unsigned char* vsn = vS + (size_t)(kt + 1) * 128;
#pragma unroll
            for (int k = 0; k < 8; ++k)
                __builtin_amdgcn_global_load_lds(
                    (const unsigned int*)(vsn + (size_t)k * 147456),
                    (unsigned int*)(vD + k * 4096), 16, 0, 0);
            asm volatile("" ::: "memory");
        }
    }

    // ---- row-sum finalize: reduce over the 32 key-lanes (within each half)
#pragma unroll
    for (int r = 0; r < 16; ++r) {
        float rs = l_acc[r];
        rs += __shfl_xor(rs, 1, 64);
        rs += __shfl_xor(rs, 2, 64);
        rs += __shfl_xor(rs, 4, 64);
        rs += __shfl_xor(rs, 8, 64);
        rs += __shfl_xor(rs, 16, 64);
        l_acc[r] = rs;
    }
    if (l31 == 0) {   // lanes 0 and 32 publish their half's 16 rows
#pragma unroll
        for (int r = 0; r < 16; ++r) {
            int row = (r & 3) + 8 * (r >> 2) + 4 * h;
            Ls[w * 32 + row] = l_acc[r];
        }
    }
    __syncthreads();   // Ls visible; also fences last PV reads before Ot reuse
    float l_tot[16];
#pragma unroll
    for (int r = 0; r < 16; ++r) {
        int row = (r & 3) + 8 * (r >> 2) + 4 * h;
        l_tot[r] = Ls[w * 32 + row] + Ls[(w ^ 1) * 32 + row];  // kb0 + kb1
    }

    // ---- epilogue: normalize, swizzled fp32 transpose, coalesced stores
    float* Ot = (float*)lds;   // [256 ch][64 q] f32, dword-XOR ((c&7)<<2)
#pragma unroll
    for (int chb = 0; chb < 4; ++chb) {
        int c = chh * 128 + chb * 32 + l31;
        int cx = (c & 7) << 2;
#pragma unroll
        for (int rr = 0; rr < 4; ++rr) {
            f4v v4;
#pragma unroll
            for (int i = 0; i < 4; ++i)
                v4[i] = acc_o[chb][rr * 4 + i] / l_tot[rr * 4 + i];
            int q0 = qb * 32 + rr * 8 + h * 4;   // rows rr*8+{0..3}+4h consecutive
            *(f4v*)(Ot + c * 64 + (q0 ^ cx)) = v4;
        }
    }
    __syncthreads();
#pragma unroll
    for (int p = 0; p < 16; ++p) {
        int c = p * 16 + (t >> 4);
        int q = (t & 15) * 4;
        f4v v4 = *(const f4v*)(Ot + c * 64 + (q ^ ((c & 7) << 2)));
        *(f4v*)(Op + (size_t)c * NTOK + qt * 64 + q) = v4;
    }
}

// ---------------------------------------------------------------------------
extern "C" void kernel_launch(void* const* d_in, const int* in_sizes, int n_in,
                              void* d_out, int out_size, void* d_ws, size_t ws_size,
                              hipStream_t stream) {
    (void)in_sizes; (void)n_in; (void)out_size; (void)ws_size;
    const float* feaL  = (const float*)d_in[0];
    const float* feaR  = (const float*)d_in[1];
    const float* Wq    = (const float*)d_in[2];
    const float* bq    = (const float*)d_in[3];
    const float* gq    = (const float*)d_in[4];
    const float* betaq = (const float*)d_in[5];
    const float* mq    = (const float*)d_in[6];
    const float* vq    = (const float*)d_in[7];
    const float* Wk    = (const float*)d_in[8];
    const float* bk    = (const float*)d_in[9];
    const float* gk    = (const float*)d_in[10];
    const float* betak = (const float*)d_in[11];
    const float* mk    = (const float*)d_in[12];
    const float* vk    = (const float*)d_in[13];

    // workspace (bf16): XT/VT alias 16*MATSZ (18.9MB) | Y 32*MATSZ (37.7MB)
    unsigned short* XT = (unsigned short*)d_ws;   // reused as VT after proj
    unsigned short* VT = XT;
    unsigned short* Yb = XT + (size_t)16 * MATSZ;
    float* out = (float*)d_out;   // fp32: reference output dtype

    // d_out-as-scratch for pre-folded weights: written by tpose1's prep
    // blocks, read by proj, then fully overwritten by attn (stream-ordered).
    unsigned short* Wbf = (unsigned short*)d_out;          // [2][256][256] bf16
    float* bias2 = (float*)(Wbf + 131072);                 // [2][256] f32

    dim3 blk(256);
    // XT[s][b][pos][c] = fea[b][c][pos]; y==16 blocks do W/BN pre-fold
    tpose_k<<<dim3(144, 17), blk, 0, stream>>>(feaL, feaR, XT, 256, 2304,
                                               Wq, Wk, bq, bk, gq, gk,
                                               betaq, betak, mq, mk, vq, vk,
                                               Wbf, bias2);
    proj_k<<<dim3(36, 16), blk, 0, stream>>>(XT, Wbf, bias2, Yb);
    // VT[s][b][c][n] = fea_flat[n*256+c]
    tpose_k<<<dim3(144, 16), blk, 0, stream>>>(feaL, feaR, VT, 2304, 256,
                                               Wq, Wk, bq, bk, gq, gk,
                                               betaq, betak, mq, mk, vq, vk,
                                               Wbf, bias2);
    attn_k<<<dim3(576), blk, 0, stream>>>(Yb, VT, out);
}

// Round 16
// 296.363 us; speedup vs baseline: 1.9036x; 1.0017x over previous
//
#include <hip/hip_runtime.h>

#define CH    256
#define NTOK  2304
#define MATSZ (CH * NTOK)   // 589824 elements per (b, matrix)

typedef __bf16 bf16x8 __attribute__((ext_vector_type(8)));
typedef float  f4v    __attribute__((ext_vector_type(4)));
typedef float  f16v   __attribute__((ext_vector_type(16)));
typedef unsigned int u32x4 __attribute__((ext_vector_type(4)));
typedef unsigned short us4 __attribute__((ext_vector_type(4)));

__device__ __forceinline__ unsigned short f2bf(float f) {
    union { float f; unsigned int i; } c;
    c.f = f;
    unsigned int x = c.i;
    x += 0x7fffu + ((x >> 16) & 1u);   // round-to-nearest-even
    return (unsigned short)(x >> 16);
}

// ---------------------------------------------------------------------------
// 64x64-tiled transpose + fp32->bf16, R16-vectorized:
//   load: 4 x float4 (coalesced 256B/row-group), store: 4 x 8B packed
//   (4x128B segments/instr). LDS tile[64][65] scalar 2B ops (R11-verified
//   2-way). 40 mem-instr/thread vs 64 scalar. Element maps identical to
//   R11-R15: tile[row][col]=f2bf(in[(r0+row)*Ccols+c0+col]);
//   out[(c0+crow)*R + r0+col] = tile[col][crow].
// mode 0: XT only, y==16 prefold (grid 144x17)   [fallback path, R13-verified order]
// mode 1: VT only (grid 144x16)                  [fallback path]
// mode 2: y0-15 XT, y16-31 VT, y32 prefold (grid 144x33) [merged, ws-guarded]
// Prefold (R12/R13-verified): Wbf=bf16(W*scale), bias2=(b-m)*scale+beta.
// ---------------------------------------------------------------------------
__global__ __launch_bounds__(256) void tpose_k(
    const float* __restrict__ inL,
    const float* __restrict__ inR,
    unsigned short* __restrict__ outA,   // XT [2][8][2304][256]
    unsigned short* __restrict__ outB,   // VT [2][8][256][2304]
    int mode,
    const float* __restrict__ Wq_, const float* __restrict__ Wk_,
    const float* __restrict__ bq_, const float* __restrict__ bk_,
    const float* __restrict__ gq_, const float* __restrict__ gk_,
    const float* __restrict__ beq_, const float* __restrict__ bek_,
    const float* __restrict__ mq_, const float* __restrict__ mk_,
    const float* __restrict__ vq_, const float* __restrict__ vk_,
    unsigned short* __restrict__ Wbf, float* __restrict__ bias2)
{
    int y = blockIdx.y;
    if ((mode == 0 && y == 16) || (mode == 2 && y == 32)) {   // W/BN pre-fold
        int i0 = ((int)blockIdx.x * 256 + (int)threadIdx.x) * 4;
#pragma unroll
        for (int j = 0; j < 4; ++j) {
            int i = i0 + j;
            if (i < 131072) {                       // 2 * 256 * 256
                int br = i >> 16, oc = i & 65535, o = oc >> 8;
                float g = br ? gk_[o] : gq_[o];
                float v = br ? vk_[o] : vq_[o];
                float scale = g * rsqrtf(v + 1e-5f);
                float wv = (br ? Wk_ : Wq_)[oc];
                Wbf[i] = f2bf(wv * scale);
            }
        }
        int ib = (int)blockIdx.x * 256 + (int)threadIdx.x;
        if (ib < 512) {
            int br = ib >> 8, o = ib & 255;
            float g = br ? gk_[o] : gq_[o];
            float v = br ? vk_[o] : vq_[o];
            float scale = g * rsqrtf(v + 1e-5f);
            float bb = br ? bk_[o] : bq_[o];
            float mm = br ? mk_[o] : mq_[o];
            float be = br ? bek_[o] : beq_[o];
            bias2[ib] = (bb - mm) * scale + be;
        }
        return;
    }

    int which = (mode == 1) ? 1 : (y >> 4);   // 0: XT (256x2304), 1: VT (2304x256)
    int mat = y & 15;
    int R     = which ? NTOK : CH;
    int Ccols = which ? CH : NTOK;
    const float* in = (mat >= 8 ? inR : inL) + (size_t)(mat & 7) * MATSZ;
    unsigned short* o = (which ? outB : outA) + (size_t)mat * MATSZ;

    __shared__ unsigned short tile[64][65];
    int tC = Ccols >> 6;
    int r0 = (blockIdx.x / tC) << 6;
    int c0 = (blockIdx.x % tC) << 6;
    int t = threadIdx.x;
    int rg = t >> 4, c4 = (t & 15) << 2;
#pragma unroll
    for (int i = 0; i < 4; ++i) {
        int row = rg + i * 16;
        f4v v = *(const f4v*)(in + (size_t)(r0 + row) * Ccols + c0 + c4);
        tile[row][c4 + 0] = f2bf(v[0]);
        tile[row][c4 + 1] = f2bf(v[1]);
        tile[row][c4 + 2] = f2bf(v[2]);
        tile[row][c4 + 3] = f2bf(v[3]);
    }
    __syncthreads();
#pragma unroll
    for (int i = 0; i < 4; ++i) {
        int crow = rg + i * 16;
        us4 v;
        v[0] = tile[c4 + 0][crow];
        v[1] = tile[c4 + 1][crow];
        v[2] = tile[c4 + 2][crow];
        v[3] = tile[c4 + 3][crow];
        *(us4*)(o + (size_t)(c0 + crow) * R + r0 + c4) = v;
    }
}

// ---------------------------------------------------------------------------
// Projection — UNCHANGED from R14/R15 (verified): one block per X tile,
// grid (36 pt, 16 sb); stages X once, loops br x ot with pre-folded bf16 W.
// ---------------------------------------------------------------------------
__global__ __launch_bounds__(256, 2) void proj_k(
    const unsigned short* __restrict__ XT,   // [2][8][2304][256] bf16
    const unsigned short* __restrict__ Wbf,  // [2][256][256] bf16 pre-scaled
    const float* __restrict__ bias2,         // [2][256] fp32
    unsigned short* __restrict__ Yout)       // [4][8][MATSZ] bf16
{
    __shared__ __align__(16) unsigned char Xs[32768];   // 64 pos x 512B, XOR
    int sb = blockIdx.y;                 // s*8 + b
    int s = sb >> 3, b = sb & 7;
    const unsigned short* X = XT + (size_t)sb * MATSZ;

    int pt = blockIdx.x;
    int pos0 = pt * 64;
    int t = threadIdx.x;
    int w = t >> 6, lane = t & 63;
    int l15 = lane & 15, quad = lane >> 4;
    int rxp = (l15 & 7) << 4;    // read-side swizzle (row&7 == l15&7)

    {   // stage XT tile once: 64 pos-rows x 256 c, linear+XOR (verified map)
        const unsigned short* src = X + (size_t)(pos0 + (t >> 5)) * CH + (t & 31) * 8;
        unsigned char* dst = Xs + ((t * 16) ^ (((t >> 5) & 7) << 4));
#pragma unroll
        for (int k = 0; k < 8; ++k)
            *(u32x4*)(dst + k * 4096) = *(const u32x4*)(src + (size_t)k * 8 * CH);
    }
    __syncthreads();

    f4v zero4 = {0.f, 0.f, 0.f, 0.f};
#pragma unroll 1
    for (int br = 0; br < 2; ++br) {
        unsigned short* Yo = Yout + (size_t)((br * 2 + s) * 8 + b) * MATSZ;
#pragma unroll 1
        for (int ot = 0; ot < 4; ++ot) {
            int o0 = ot * 64;
            bf16x8 wf[8];
            {
                const unsigned short* wp = Wbf + (size_t)br * 65536
                                         + (size_t)(o0 + w * 16 + l15) * CH + quad * 8;
#pragma unroll
                for (int kc = 0; kc < 8; ++kc)
                    wf[kc] = *(const bf16x8*)(wp + kc * 32);
            }
            f4v acc[4] = {zero4, zero4, zero4, zero4};
#pragma unroll
            for (int kc = 0; kc < 8; ++kc) {
#pragma unroll
                for (int ct = 0; ct < 4; ++ct) {
                    int row = ct * 16 + l15;
                    bf16x8 xb = *(const bf16x8*)(Xs + (row << 9)
                                               + (((kc << 6) + (quad << 4)) ^ rxp));
                    acc[ct] = __builtin_amdgcn_mfma_f32_16x16x32_bf16(wf[kc], xb, acc[ct], 0, 0, 0);
                }
            }
#pragma unroll
            for (int r = 0; r < 4; ++r) {
                int o = o0 + w * 16 + quad * 4 + r;
                float shift = bias2[br * 256 + o];
#pragma unroll
                for (int ct = 0; ct < 4; ++ct) {
                    float val = acc[ct][r] + shift;
                    Yo[(size_t)o * NTOK + pos0 + ct * 16 + l15] = f2bf(val);
                }
            }
        }
    }
}

// ---------------------------------------------------------------------------
// Fused attention — UNCHANGED from R10-R15 (verified 164.6-166.2us):
// 32x32x16 compute + phase-shifted glld issue + counted vmcnt (T3/T4).
// ---------------------------------------------------------------------------
__global__ __launch_bounds__(256, 2) void attn_k(
    const unsigned short* __restrict__ Y,    // [4][8][MATSZ] projections bf16
    const unsigned short* __restrict__ VT,   // [2][8][256][2304] bf16
    float* __restrict__ out)                 // [2][8][MATSZ] fp32
{
    __shared__ __align__(16) unsigned char lds[74240];
    unsigned char* Ks = lds;                    // 32768
    unsigned char* Vs = lds + 32768;            // 32768
    unsigned char* Pb = lds + 65536;            // 8192
    float*         Ls = (float*)(lds + 73728);  // [4][32] f32

    int bid = blockIdx.x;
    int wg = (bid & 7) * 72 + (bid >> 3);   // XCD swizzle (576 = 8*72, bijective)
    int qt = wg % 36;
    int ab = wg / 36;
    int a = ab >> 3, b = ab & 7;
    const unsigned short* Qp = Y + (size_t)(a * 8 + b) * MATSZ;        // q(l)/q(r)
    const unsigned short* Kp = Y + (size_t)((3 - a) * 8 + b) * MATSZ;  // k(r)/k(l)
    const unsigned short* Vp = VT + (size_t)((1 - a) * 8 + b) * MATSZ;
    float* Op = out + (size_t)ab * MATSZ;

    int t = threadIdx.x;
    int w = t >> 6, lane = t & 63;
    int l31 = lane & 31, h = lane >> 5;
    int qb = w >> 1;             // q-block (QK^T and PV)
    int kb = w & 1;              // key-block (QK^T)
    int chh = w & 1;             // channel-half (PV)
    int rxor = (l31 & 7) << 4;   // read-side swizzle (row&7 == l31&7 everywhere)

    // staging addresses: linear LDS dest, inverse-swizzled global source (R4)
    const unsigned char* kS = (const unsigned char*)Kp
        + ((t * 16) ^ (((t >> 5) & 7) << 4));                 // + kt*32768 + k*4096
    const unsigned char* vS = (const unsigned char*)Vp
        + (size_t)(t >> 3) * 4608
        + (((t & 7) * 16) ^ (((t >> 3) & 7) << 4));           // + kt*128 + k*147456
    unsigned char* kD = Ks + t * 16;                          // + k*4096
    unsigned char* vD = Vs + t * 16;                          // + k*4096

    // Q fragments in registers: rows qt*64 + qb*32 + l31, A-frag k = h*8+j
    bf16x8 qf[16];
    {
        const unsigned short* qp = Qp + (size_t)(qt * 64 + qb * 32 + l31) * CH + h * 8;
#pragma unroll
        for (int ks = 0; ks < 16; ++ks)
            qf[ks] = *(const bf16x8*)(qp + ks * 16);
    }

    f16v acc_o[4];
#pragma unroll
    for (int c = 0; c < 4; ++c)
#pragma unroll
        for (int r = 0; r < 16; ++r) acc_o[c][r] = 0.f;
    float l_acc[16];
#pragma unroll
    for (int r = 0; r < 16; ++r) l_acc[r] = 0.f;

    // prologue: issue K(0) then V(0); asm sep pins issue order for vmcnt math
#pragma unroll
    for (int k = 0; k < 8; ++k)
        __builtin_amdgcn_global_load_lds(
            (const unsigned int*)(kS + k * 4096),
            (unsigned int*)(kD + k * 4096), 16, 0, 0);
    asm volatile("" ::: "memory");
#pragma unroll
    for (int k = 0; k < 8; ++k)
        __builtin_amdgcn_global_load_lds(
            (const unsigned int*)(vS + (size_t)k * 147456),
            (unsigned int*)(vD + k * 4096), 16, 0, 0);

    for (int kt = 0; kt < 36; ++kt) {
        // (1) drain K(kt); V(kt)'s 8 stay in flight
        asm volatile("s_waitcnt vmcnt(8)" ::: "memory");
        __builtin_amdgcn_s_barrier();            // (2) B1: K(kt) visible
        asm volatile("" ::: "memory");

        // (3) QK^T: S[qb*32..+32][kb*32..+32], 16 k-steps
        f16v accs;
#pragma unroll
        for (int r = 0; r < 16; ++r) accs[r] = 0.f;
        const unsigned char* krow = Ks + ((kb * 32 + l31) << 9);
#pragma unroll
        for (int ks = 0; ks < 16; ++ks) {
            bf16x8 kf = *(const bf16x8*)(krow + ((ks * 32 + h * 16) ^ rxor));
            accs = __builtin_amdgcn_mfma_f32_32x32x16_bf16(qf[ks], kf, accs, 0, 0, 0);
        }
        // exp, partial row-sums, P write (C-layout row=(r&3)+8*(r>>2)+4h)
#pragma unroll
        for (int r = 0; r < 16; ++r) {
            float pe = __expf(accs[r] * (1.0f / 256.0f));
            l_acc[r] += pe;
            int row = (r & 3) + 8 * (r >> 2) + 4 * h;   // q within qb*32
            int q = qb * 32 + row;
            *(__bf16*)(Pb + q * 128 + ((kb * 64 + l31 * 2) ^ ((row & 7) << 4))) = (__bf16)pe;
        }
        // (4) drain V(kt) (hidden under QK^T) + P-writes
        asm volatile("s_waitcnt vmcnt(0) lgkmcnt(0)" ::: "memory");
        __builtin_amdgcn_s_barrier();            // (5) B2: P+V visible; K free
        asm volatile("" ::: "memory");

        // (6) issue K(kt+1): K readers done at B2
        if (kt < 35) {
            const unsigned char* ksn = kS + (size_t)(kt + 1) * 32768;
#pragma unroll
            for (int k = 0; k < 8; ++k)
                __builtin_amdgcn_global_load_lds(
                    (const unsigned int*)(ksn + k * 4096),
                    (unsigned int*)(kD + k * 4096), 16, 0, 0);
            asm volatile("" ::: "memory");
        }

        // (7) PV: O[qb*32..+32][chh*128..+128]
#pragma unroll
        for (int ks2 = 0; ks2 < 4; ++ks2) {
            bf16x8 pf = *(const bf16x8*)(Pb + ((qb * 32 + l31) << 7)
                                       + ((ks2 * 32 + h * 16) ^ rxor));
#pragma unroll
            for (int chb = 0; chb < 4; ++chb) {
                int ch = chh * 128 + chb * 32 + l31;
                bf16x8 vf = *(const bf16x8*)(Vs + (ch << 7)
                                           + ((ks2 * 32 + h * 16) ^ rxor));
                acc_o[chb] = __builtin_amdgcn_mfma_f32_32x32x16_bf16(pf, vf, acc_o[chb], 0, 0, 0);
            }
        }

        __builtin_amdgcn_s_barrier();            // (8) B0: V/P readers done
        asm volatile("" ::: "memory");

        // (9) issue V(kt+1)
        if (kt < 35) {
            const unsigned char* vsn = vS + (size_t)(kt + 1) * 128;
#pragma unroll
            for (int k = 0; k < 8; ++k)
                __builtin_amdgcn_global_load_lds(
                    (const unsigned int*)(vsn + (size_t)k * 147456),
                    (unsigned int*)(vD + k * 4096), 16, 0, 0);
            asm volatile("" ::: "memory");
        }
    }

    // ---- row-sum finalize: reduce over the 32 key-lanes (within each half)
#pragma unroll
    for (int r = 0; r < 16; ++r) {
        float rs = l_acc[r];
        rs += __shfl_xor(rs, 1, 64);
        rs += __shfl_xor(rs, 2, 64);
        rs += __shfl_xor(rs, 4, 64);
        rs += __shfl_xor(rs, 8, 64);
        rs += __shfl_xor(rs, 16, 64);
        l_acc[r] = rs;
    }
    if (l31 == 0) {   // lanes 0 and 32 publish their half's 16 rows
#pragma unroll
        for (int r = 0; r < 16; ++r) {
            int row = (r & 3) + 8 * (r >> 2) + 4 * h;
            Ls[w * 32 + row] = l_acc[r];
        }
    }
    __syncthreads();   // Ls visible; also fences last PV reads before Ot reuse
    float l_tot[16];
#pragma unroll
    for (int r = 0; r < 16; ++r) {
        int row = (r & 3) + 8 * (r >> 2) + 4 * h;
        l_tot[r] = Ls[w * 32 + row] + Ls[(w ^ 1) * 32 + row];  // kb0 + kb1
    }

    // ---- epilogue: normalize, swizzled fp32 transpose, coalesced stores
    float* Ot = (float*)lds;   // [256 ch][64 q] f32, dword-XOR ((c&7)<<2)
#pragma unroll
    for (int chb = 0; chb < 4; ++chb) {
        int c = chh * 128 + chb * 32 + l31;
        int cx = (c & 7) << 2;
#pragma unroll
        for (int rr = 0; rr < 4; ++rr) {
            f4v v4;
#pragma unroll
            for (int i = 0; i < 4; ++i)
                v4[i] = acc_o[chb][rr * 4 + i] / l_tot[rr * 4 + i];
            int q0 = qb * 32 + rr * 8 + h * 4;   // rows rr*8+{0..3}+4h consecutive
            *(f4v*)(Ot + c * 64 + (q0 ^ cx)) = v4;
        }
    }
    __syncthreads();
#pragma unroll
    for (int p = 0; p < 16; ++p) {
        int c = p * 16 + (t >> 4);
        int q = (t & 15) * 4;
        f4v v4 = *(const f4v*)(Ot + c * 64 + (q ^ ((c & 7) << 2)));
        *(f4v*)(Op + (size_t)c * NTOK + qt * 64 + q) = v4;
    }
}

// ---------------------------------------------------------------------------
extern "C" void kernel_launch(void* const* d_in, const int* in_sizes, int n_in,
                              void* d_out, int out_size, void* d_ws, size_t ws_size,
                              hipStream_t stream) {
    (void)in_sizes; (void)n_in; (void)out_size;
    const float* feaL  = (const float*)d_in[0];
    const float* feaR  = (const float*)d_in[1];
    const float* Wq    = (const float*)d_in[2];
    const float* bq    = (const float*)d_in[3];
    const float* gq    = (const float*)d_in[4];
    const float* betaq = (const float*)d_in[5];
    const float* mq    = (const float*)d_in[6];
    const float* vq    = (const float*)d_in[7];
    const float* Wk    = (const float*)d_in[8];
    const float* bk    = (const float*)d_in[9];
    const float* gk    = (const float*)d_in[10];
    const float* betak = (const float*)d_in[11];
    const float* mk    = (const float*)d_in[12];
    const float* vk    = (const float*)d_in[13];

    unsigned short* XT = (unsigned short*)d_ws;            // 16*MATSZ shorts
    unsigned short* Yb = XT + (size_t)16 * MATSZ;          // 32*MATSZ shorts
    float* out = (float*)d_out;

    // d_out-as-scratch for pre-folded weights (R12/R13-verified ordering).
    unsigned short* Wbf = (unsigned short*)d_out;          // [2][256][256] bf16
    float* bias2 = (float*)(Wbf + 131072);                 // [2][256] f32

    dim3 blk(256);
    size_t need = (size_t)64 * MATSZ * 2;   // XT 16 + Y 32 + VT 16 (MATSZ shorts)
    if (ws_size >= need) {
        // merged path: VT gets its own region; one transpose launch total
        unsigned short* VT = Yb + (size_t)32 * MATSZ;
        tpose_k<<<dim3(144, 33), blk, 0, stream>>>(feaL, feaR, XT, VT, 2,
                                                   Wq, Wk, bq, bk, gq, gk,
                                                   betaq, betak, mq, mk, vq, vk,
                                                   Wbf, bias2);
        proj_k<<<dim3(36, 16), blk, 0, stream>>>(XT, Wbf, bias2, Yb);
        attn_k<<<dim3(576), blk, 0, stream>>>(Yb, VT, out);
    } else {
        // fallback: R15-verified ordering (VT aliases XT after proj)
        unsigned short* VT = XT;
        tpose_k<<<dim3(144, 17), blk, 0, stream>>>(feaL, feaR, XT, XT, 0,
                                                   Wq, Wk, bq, bk, gq, gk,
                                                   betaq, betak, mq, mk, vq, vk,
                                                   Wbf, bias2);
        proj_k<<<dim3(36, 16), blk, 0, stream>>>(XT, Wbf, bias2, Yb);
        tpose_k<<<dim3(144, 16), blk, 0, stream>>>(feaL, feaR, XT, VT, 1,
                                                   Wq, Wk, bq, bk, gq, gk,
                                                   betaq, betak, mq, mk, vq, vk,
                                                   Wbf, bias2);
        attn_k<<<dim3(576), blk, 0, stream>>>(Yb, VT, out);
    }
}